// Round 16
// baseline (2387.916 us; speedup 1.0000x reference)
//
#include <hip/hip_runtime.h>
#include <math.h>

// TransformerLanguageModel forward on MI355X (gfx950).
// R16: revert R15's Wo split-K (byte audit: partial-buffer traffic exceeded
//      staging saved for K=1024/N=1024 -- regression +73us matched the +~70us
//      predicted from +"40-64MB/layer" at 6TB/s supply). Wo back to gemm_p
//      with fused residual + separate LN (R14-proven). Split-K retained ONLY
//      for FF2 (K=4096: staging saved 256MB > partial traffic 128MB).
//      attn setprio kept (exonerated by the traffic arithmetic).

using u16 = unsigned short;
using u32 = unsigned int;
typedef __attribute__((ext_vector_type(4))) float  f32x4;
typedef __attribute__((ext_vector_type(8))) short  s16x8;
typedef __attribute__((ext_vector_type(8))) __bf16 bf16x8;

__device__ __forceinline__ u16 f2bf(float f) {
  u32 u = __builtin_bit_cast(u32, f);
  u += 0x7fffu + ((u >> 16) & 1u);   // round-to-nearest-even
  return (u16)(u >> 16);
}

__device__ __forceinline__ f32x4 mfma16(s16x8 a, s16x8 b, f32x4 c) {
  return __builtin_amdgcn_mfma_f32_16x16x32_bf16(
      __builtin_bit_cast(bf16x8, a), __builtin_bit_cast(bf16x8, b), c, 0, 0, 0);
}

#define GLD16(gp, lp) __builtin_amdgcn_global_load_lds(                    \
    (const __attribute__((address_space(1))) void*)(gp),                   \
    (__attribute__((address_space(3))) void*)(lp), 16, 0, 0)

// ---------------- weight transpose + f32->bf16 convert ----------------
// in tile: rows bx*64..+63, cols by*32..+31  ->  out[by*32+r][bx*64+c]
__global__ __launch_bounds__(256) void transpose_cvt2(
    const float* __restrict__ in, u16* __restrict__ out,
    int C, long long inLS, long long outLS, int outRS)
{
  __shared__ float t[32][65];
  int tid = threadIdx.x;
  const float* ip = in + (size_t)blockIdx.z * inLS +
                    ((size_t)blockIdx.x * 64) * C + blockIdx.y * 32;
#pragma unroll
  for (int it = 0; it < 8; ++it) {
    int idx = it * 256 + tid;
    int ir = idx >> 5, ic = idx & 31;
    t[ic][ir] = ip[(size_t)ir * C + ic];
  }
  __syncthreads();
  int r = tid >> 3, c0 = (tid & 7) * 8;
  u16* op = out + (size_t)blockIdx.z * outLS +
            ((size_t)blockIdx.y * 32 + r) * outRS + blockIdx.x * 64 + c0;
  const float* src = &t[r][c0];
  uint4 q;
  q.x = (u32)f2bf(src[0]) | ((u32)f2bf(src[1]) << 16);
  q.y = (u32)f2bf(src[2]) | ((u32)f2bf(src[3]) << 16);
  q.z = (u32)f2bf(src[4]) | ((u32)f2bf(src[5]) << 16);
  q.w = (u32)f2bf(src[6]) | ((u32)f2bf(src[7]) << 16);
  *(uint4*)op = q;
}

__global__ __launch_bounds__(256) void pack_bqkv(
    const float* __restrict__ bq, const float* __restrict__ bk,
    const float* __restrict__ bv, float* __restrict__ outb)
{
  int i = blockIdx.x * 256 + threadIdx.x;  // 8*3072 total
  int ly = i / 3072, j = i % 3072;
  float v = (j < 1024) ? bq[ly * 1024 + j]
          : (j < 2048) ? bk[ly * 1024 + (j - 1024)]
                       : bv[ly * 1024 + (j - 2048)];
  outb[i] = v;
}

// ---------------- embedding + positional encoding ----------------
__global__ __launch_bounds__(256) void embed_kernel(
    const int* __restrict__ tokens, const float* __restrict__ embW,
    float* __restrict__ x)
{
  int row = blockIdx.x;            // b*1024 + s
  int s = row & 1023;
  int tok = tokens[row];
  int d0 = threadIdx.x * 4;
  float4 e = *(const float4*)&embW[(size_t)tok * 1024 + d0];
  const float c = -9.210340371976184f / 1024.0f;  // -ln(10000)/D
  float div0 = expf((float)d0 * c);
  float div1 = expf((float)(d0 + 2) * c);
  float sn0, cs0, sn1, cs1;
  sincosf((float)s * div0, &sn0, &cs0);
  sincosf((float)s * div1, &sn1, &cs1);
  float4 r;
  r.x = e.x + sn0; r.y = e.y + cs0; r.z = e.z + sn1; r.w = e.w + cs1;
  *(float4*)&x[(size_t)row * 1024 + d0] = r;
}

// ---------------- layernorm (f32 in -> bf16 out) ----------------
__global__ __launch_bounds__(256) void ln_kernel(
    const float* __restrict__ x, const float* __restrict__ g,
    const float* __restrict__ b, u16* __restrict__ y)
{
  int row = blockIdx.x, tid = threadIdx.x;
  float4 v = *(const float4*)&x[(size_t)row * 1024 + tid * 4];
  float sum = v.x + v.y + v.z + v.w;
  float sq = v.x * v.x + v.y * v.y + v.z * v.z + v.w * v.w;
#pragma unroll
  for (int o = 32; o > 0; o >>= 1) {
    sum += __shfl_xor(sum, o, 64);
    sq  += __shfl_xor(sq,  o, 64);
  }
  __shared__ float ps[8];
  int w = tid >> 6;
  if ((tid & 63) == 0) { ps[w] = sum; ps[4 + w] = sq; }
  __syncthreads();
  sum = ps[0] + ps[1] + ps[2] + ps[3];
  sq  = ps[4] + ps[5] + ps[6] + ps[7];
  float mu = sum * (1.0f / 1024.0f);
  float var = sq * (1.0f / 1024.0f) - mu * mu;
  float rs = rsqrtf(var + 1e-5f);
  float4 gg = *(const float4*)&g[tid * 4];
  float4 bb = *(const float4*)&b[tid * 4];
  u32 lo = (u32)f2bf((v.x - mu) * rs * gg.x + bb.x) |
           ((u32)f2bf((v.y - mu) * rs * gg.y + bb.y) << 16);
  u32 hi = (u32)f2bf((v.z - mu) * rs * gg.z + bb.z) |
           ((u32)f2bf((v.w - mu) * rs * gg.w + bb.w) << 16);
  uint2 o2; o2.x = lo; o2.y = hi;
  *(uint2*)&y[(size_t)row * 1024 + tid * 4] = o2;
}

// ---------------- split-K reduce + residual + LayerNorm fused ----------
// x += p0+p1+p2+p3 + bias;  y = LN(x; g,b)
__global__ __launch_bounds__(256) void red_ln(
    const float* __restrict__ p, const float* __restrict__ bias,
    float* __restrict__ x, const float* __restrict__ g,
    const float* __restrict__ b, u16* __restrict__ y)
{
  int row = blockIdx.x, tid = threadIdx.x;
  size_t idx = (size_t)row * 1024 + tid * 4;
  f32x4 v  = *(f32x4*)&x[idx];
  v = v + *(const f32x4*)&p[idx]
        + *(const f32x4*)&p[idx + 4194304]
        + *(const f32x4*)&p[idx + 8388608]
        + *(const f32x4*)&p[idx + 12582912]
        + *(const f32x4*)&bias[tid * 4];
  *(f32x4*)&x[idx] = v;
  float sum = v.x + v.y + v.z + v.w;
  float sq  = v.x * v.x + v.y * v.y + v.z * v.z + v.w * v.w;
#pragma unroll
  for (int o = 32; o > 0; o >>= 1) {
    sum += __shfl_xor(sum, o, 64);
    sq  += __shfl_xor(sq,  o, 64);
  }
  __shared__ float ps[8];
  int w = tid >> 6;
  if ((tid & 63) == 0) { ps[w] = sum; ps[4 + w] = sq; }
  __syncthreads();
  sum = ps[0] + ps[1] + ps[2] + ps[3];
  sq  = ps[4] + ps[5] + ps[6] + ps[7];
  float mu = sum * (1.0f / 1024.0f);
  float var = sq * (1.0f / 1024.0f) - mu * mu;
  float rs = rsqrtf(var + 1e-5f);
  float4 gg = *(const float4*)&g[tid * 4];
  float4 bb = *(const float4*)&b[tid * 4];
  u32 lo = (u32)f2bf((v.x - mu) * rs * gg.x + bb.x) |
           ((u32)f2bf((v.y - mu) * rs * gg.y + bb.y) << 16);
  u32 hi = (u32)f2bf((v.z - mu) * rs * gg.z + bb.z) |
           ((u32)f2bf((v.w - mu) * rs * gg.w + bb.w) << 16);
  uint2 o2; o2.x = lo; o2.y = hi;
  *(uint2*)&y[idx] = o2;
}

// ---------------- GEMM 256x256, BK=64, 8 waves, ring-2, 1 barrier/K-tile -
// (R12-verified form.)  C[M,N] = A[M,K] @ Bt[N,K] + bias.
// OMODE 0: bf16 out; 2: f32 out; 3: f32 partial (no bias; Cp + split*M*N).
// MAP 0: 4x8 super-tiles per XCD.  MAP 1: split-K=4 (offset split*klen).
template<int OMODE, int RELU, int MAP>
__global__ __launch_bounds__(512, 2) void gemm256(
    const u16* __restrict__ A, int lda, const u16* __restrict__ Bt,
    const float* __restrict__ bias, void* Cp, int M, int N, int klen,
    int gxp8, int gxreal)
{
  __shared__ alignas(16) u16 lds[2][32768];
  const int tid = threadIdx.x;
  const int w = tid >> 6, l = tid & 63;
  const int g = l >> 4, lr = l & 15;
  const int wm = w >> 2, wn = w & 3;            // 2 x 4 waves, wave tile 128x64
  const int bid = blockIdx.x;
  const int xcd = bid & 7, k = bid >> 3;
  int by, bx, split = 0;
  if (MAP == 0) {
    int t = k >> 5, j = k & 31;
    int s = xcd + 8 * t;
    by = (s / gxp8) * 4 + (j & 3);
    bx = (s % gxp8) * 8 + (j >> 2);
    if (bx >= gxreal) return;
  } else {
    split = bid & 3;
    by = (bid >> 2) & 15;
    bx = bid >> 6;
  }
  const int m0 = by << 8, n0 = bx << 8;
  const u16* Ab = A  + (size_t)split * klen;    // K-offset for split-K
  const u16* Bb = Bt + (size_t)split * klen;

  // staging: 4 x 16B for A and 4 x 16B for B per thread per K-tile.
  const u16* Ag[4]; const u16* Bg[4]; int dstE[4];
#pragma unroll
  for (int s2 = 0; s2 < 4; ++s2) {
    int idx = s2 * 512 + tid;
    int row = idx >> 3;
    int ch = (idx & 7) ^ (row & 7);             // involutive chunk swizzle
    Ag[s2] = Ab + (size_t)(m0 + row) * lda + ch * 8;
    Bg[s2] = Bb + (size_t)(n0 + row) * lda + ch * 8;
    dstE[s2] = idx * 8;
  }
  // fragment reads: logical chunk (ks*4+g) at physical (ks*4+g)^(lr&7)
  const int colx0 = ((g)     ^ (lr & 7)) * 8;   // ks=0
  const int colx1 = ((4 + g) ^ (lr & 7)) * 8;   // ks=1
  const int abase = (wm * 128 + lr) * 64;           // + mf*1024 + colx
  const int bbase = 16384 + (wn * 64 + lr) * 64;    // + nf*1024 + colx

  f32x4 acc[8][4];
#pragma unroll
  for (int i = 0; i < 8; ++i)
#pragma unroll
    for (int j2 = 0; j2 < 4; ++j2) acc[i][j2] = f32x4{0.f, 0.f, 0.f, 0.f};

  const int nk = klen >> 6;
  // prologue: stage tile 0
#pragma unroll
  for (int s2 = 0; s2 < 4; ++s2) GLD16(Ag[s2], &lds[0][dstE[s2]]);
#pragma unroll
  for (int s2 = 0; s2 < 4; ++s2) GLD16(Bg[s2], &lds[0][16384 + dstE[s2]]);
  asm volatile("s_waitcnt vmcnt(0)" ::: "memory");   // my tile-0 loads landed
  __builtin_amdgcn_s_barrier();                      // => ALL waves' landed (R4 rule)

  int cur = 0;
  for (int t = 0; t < nk; ++t) {
    const bool more = (t + 1 < nk);
    // next-tile GLDs first (max in-flight time). Overwrites lds[cur^1] =
    // tile t-1: all waves' reads of it completed before their iter-(t-1)
    // MFMA, hence before the iter-(t-1) barrier (R6-proven).
    if (more) {
      const int kn = (t + 1) << 6;
#pragma unroll
      for (int s2 = 0; s2 < 4; ++s2) GLD16(Ag[s2] + kn, &lds[cur ^ 1][dstE[s2]]);
#pragma unroll
      for (int s2 = 0; s2 < 4; ++s2) GLD16(Bg[s2] + kn, &lds[cur ^ 1][16384 + dstE[s2]]);
    }
    s16x8 a0[8], b0[4], a1[8], b1[4];
#pragma unroll
    for (int mf = 0; mf < 8; ++mf) a0[mf] = *(const s16x8*)&lds[cur][abase + mf * 1024 + colx0];
#pragma unroll
    for (int nf = 0; nf < 4; ++nf) b0[nf] = *(const s16x8*)&lds[cur][bbase + nf * 1024 + colx0];
#pragma unroll
    for (int mf = 0; mf < 8; ++mf) a1[mf] = *(const s16x8*)&lds[cur][abase + mf * 1024 + colx1];
#pragma unroll
    for (int nf = 0; nf < 4; ++nf) b1[nf] = *(const s16x8*)&lds[cur][bbase + nf * 1024 + colx1];
    __builtin_amdgcn_s_setprio(1);
#pragma unroll
    for (int mf = 0; mf < 8; ++mf)
#pragma unroll
      for (int nf = 0; nf < 4; ++nf) acc[mf][nf] = mfma16(a0[mf], b0[nf], acc[mf][nf]);
#pragma unroll
    for (int mf = 0; mf < 8; ++mf)
#pragma unroll
      for (int nf = 0; nf < 4; ++nf) acc[mf][nf] = mfma16(a1[mf], b1[nf], acc[mf][nf]);
    __builtin_amdgcn_s_setprio(0);
    if (more) {
      asm volatile("s_waitcnt vmcnt(0)" ::: "memory");
      __builtin_amdgcn_s_barrier();
      cur ^= 1;
    }
  }

  // ---- epilogue: LDS-staged, full-cache-line vectorized stores (R8) ----
  float* fst = (float*)(void*)&lds[0][0];
  float* Cf = (OMODE == 3)
            ? ((float*)Cp + (size_t)split * ((size_t)M * N))
            : (float*)Cp;
#pragma unroll
  for (int mf = 0; mf < 8; ++mf) {
    __builtin_amdgcn_s_barrier();        // prior round's LDS reads complete
#pragma unroll
    for (int nf = 0; nf < 4; ++nf) {
      int cl = wn * 64 + nf * 16 + lr;
      float bv = 0.f;
      if (OMODE != 3) bv = bias[n0 + cl];
      int rl = wm * 16 + g * 4;
#pragma unroll
      for (int r = 0; r < 4; ++r) {
        float v = acc[mf][nf][r] + bv;
        if (RELU) v = fmaxf(v, 0.f);
        fst[(rl + r) * 260 + cl] = v;    // banks: 2-way (free)
      }
    }
    __builtin_amdgcn_s_barrier();
    if (OMODE == 0) {
      // 32 rows x 256 bf16 = 1024 segs of 16B
#pragma unroll
      for (int it = 0; it < 2; ++it) {
        int seg = it * 512 + tid;
        int row = seg >> 5;
        int co  = (seg & 31) * 8;
        int grow = m0 + (row >> 4) * 128 + mf * 16 + (row & 15);
        const float* src = &fst[row * 260 + co];
        uint4 q;
        q.x = (u32)f2bf(src[0]) | ((u32)f2bf(src[1]) << 16);
        q.y = (u32)f2bf(src[2]) | ((u32)f2bf(src[3]) << 16);
        q.z = (u32)f2bf(src[4]) | ((u32)f2bf(src[5]) << 16);
        q.w = (u32)f2bf(src[6]) | ((u32)f2bf(src[7]) << 16);
        *(uint4*)&((u16*)Cp)[(size_t)grow * N + n0 + co] = q;
      }
    } else {
      // 32 rows x 256 f32 = 2048 segs of 16B
#pragma unroll
      for (int it = 0; it < 4; ++it) {
        int seg = it * 512 + tid;
        int row = seg >> 6;
        int co  = (seg & 63) * 4;
        int grow = m0 + (row >> 4) * 128 + mf * 16 + (row & 15);
        f32x4 q = *(const f32x4*)&fst[row * 260 + co];
        *(f32x4*)&Cf[(size_t)grow * N + n0 + co] = q;
      }
    }
  }
}

// ---------------- GEMM 128x128, 4 waves, ring-2, 1 barrier/K-tile --------
// For N=1024 shapes (Wo, FF2 fallback). OMODE 1: f32 out + residual add.
template<int OMODE, int RELU>
__global__ __launch_bounds__(256, 3) void gemm_p(
    const u16* __restrict__ A, const u16* __restrict__ Bt,
    const float* __restrict__ bias, const float* res, void* Cp,
    int M, int N, int K, int gx)
{
  __shared__ alignas(16) u16 lds[2][8192];
  const int tid = threadIdx.x;
  const int w = tid >> 6, l = tid & 63;
  const int g = l >> 4, lr = l & 15;
  const int wm = w >> 1, wn = w & 1;
  int nwg = gridDim.x;
  int bid = blockIdx.x;
  int swz = (bid & 7) * (nwg >> 3) + (bid >> 3);
  int bx = swz % gx, by = swz / gx;
  int m0 = by << 7, n0 = bx << 7;

  const u16 *Ag[2], *Bg[2];
  int dstA[2], dstB[2];
#pragma unroll
  for (int s = 0; s < 2; ++s) {
    int idx = s * 256 + tid;
    int row = idx >> 2;
    int ch = (idx & 3) ^ ((row >> 1) & 3);
    Ag[s] = A  + (size_t)(m0 + row) * K + ch * 8;
    Bg[s] = Bt + (size_t)(n0 + row) * K + ch * 8;
    dstA[s] = idx * 8;
    dstB[s] = 4096 + idx * 8;
  }
  const int colx = (g ^ ((lr >> 1) & 3)) * 8;
  const int aoff = (wm * 64 + lr) * 32 + colx;
  const int boff = 4096 + (wn * 64 + lr) * 32 + colx;

  f32x4 acc[4][4];
#pragma unroll
  for (int i = 0; i < 4; ++i)
#pragma unroll
    for (int j = 0; j < 4; ++j) acc[i][j] = f32x4{0.f, 0.f, 0.f, 0.f};

  const int nk = K >> 5;
#pragma unroll
  for (int s = 0; s < 2; ++s) GLD16(Ag[s], &lds[0][dstA[s]]);
#pragma unroll
  for (int s = 0; s < 2; ++s) GLD16(Bg[s], &lds[0][dstB[s]]);
  asm volatile("s_waitcnt vmcnt(0)" ::: "memory");
  __builtin_amdgcn_s_barrier();

  int cur = 0;
  s16x8 aC[4], bC[4];
#pragma unroll
  for (int i = 0; i < 4; ++i) aC[i] = *(const s16x8*)&lds[0][aoff + i * 512];
#pragma unroll
  for (int j = 0; j < 4; ++j) bC[j] = *(const s16x8*)&lds[0][boff + j * 512];

  for (int t = 0; t < nk; ++t) {
    const bool more = (t + 1 < nk);
    if (more) {
      const int kn = (t + 1) << 5;
#pragma unroll
      for (int s = 0; s < 2; ++s) GLD16(Ag[s] + kn, &lds[cur ^ 1][dstA[s]]);
#pragma unroll
      for (int s = 0; s < 2; ++s) GLD16(Bg[s] + kn, &lds[cur ^ 1][dstB[s]]);
    }
    __builtin_amdgcn_s_setprio(1);
#pragma unroll
    for (int i = 0; i < 4; ++i)
#pragma unroll
      for (int j = 0; j < 4; ++j) acc[i][j] = mfma16(aC[i], bC[j], acc[i][j]);
    __builtin_amdgcn_s_setprio(0);
    if (more) {
      asm volatile("s_waitcnt vmcnt(0)" ::: "memory");
      __builtin_amdgcn_s_barrier();
      cur ^= 1;
#pragma unroll
      for (int i = 0; i < 4; ++i) aC[i] = *(const s16x8*)&lds[cur][aoff + i * 512];
#pragma unroll
      for (int j = 0; j < 4; ++j) bC[j] = *(const s16x8*)&lds[cur][boff + j * 512];
    }
  }
#pragma unroll
  for (int mf = 0; mf < 4; ++mf) {
    int row = m0 + wm * 64 + mf * 16 + g * 4;
#pragma unroll
    for (int nf = 0; nf < 4; ++nf) {
      int col = n0 + wn * 64 + nf * 16 + lr;
      float bv = bias[col];
#pragma unroll
      for (int r = 0; r < 4; ++r) {
        float v = acc[mf][nf][r] + bv;
        if (RELU) v = fmaxf(v, 0.f);
        size_t idx = (size_t)(row + r) * N + col;
        if (OMODE == 0)      ((u16*)Cp)[idx] = f2bf(v);
        else if (OMODE == 1) ((float*)Cp)[idx] = v + res[idx];
        else                 ((float*)Cp)[idx] = v;
      }
    }
  }
}

// ---------------- flash attention ----------------
__global__ __launch_bounds__(256) void attn_kernel(
    const u16* __restrict__ qkv, u16* __restrict__ outp)
{
  int b = blockIdx.x >> 4, h = blockIdx.x & 15;
  int q0 = blockIdx.y << 6;
  int tid = threadIdx.x, w = tid >> 6, l = tid & 63;
  int g = l >> 4, lr = l & 15;
  const int RS = 3072;
  const u16* base = qkv + (size_t)b * 1024 * RS + h * 64;
  const u16* Qb = base;
  const u16* Kb = base + 1024;
  const u16* Vb = base + 2048;
  __shared__ alignas(16) u16 Plds[4][1024];
  __shared__ alignas(16) u16 Vt[4096];
  char* Pw = (char*)&Plds[w][0];

  s16x8 qf[2];
#pragma unroll
  for (int ks = 0; ks < 2; ++ks)
    qf[ks] = *(const s16x8*)&Qb[(size_t)(q0 + w * 16 + lr) * RS + ks * 32 + g * 8];

  f32x4 o[4];
#pragma unroll
  for (int n = 0; n < 4; ++n) o[n] = f32x4{0.f, 0.f, 0.f, 0.f};
  float mr[4] = {-INFINITY, -INFINITY, -INFINITY, -INFINITY};
  float ls[4] = {0.f, 0.f, 0.f, 0.f};

  int ntile = (q0 >> 6) + 1;
  for (int kt = 0; kt < ntile; ++kt) {
    int kv0 = kt << 6;
    f32x4 sc[4];
#pragma unroll
    for (int t = 0; t < 4; ++t) sc[t] = f32x4{0.f, 0.f, 0.f, 0.f};
    __builtin_amdgcn_s_setprio(1);
#pragma unroll
    for (int ks = 0; ks < 2; ++ks)
#pragma unroll
      for (int t = 0; t < 4; ++t) {
        s16x8 kf = *(const s16x8*)&Kb[(size_t)(kv0 + t * 16 + lr) * RS + ks * 32 + g * 8];
        sc[t] = mfma16(qf[ks], kf, sc[t]);
      }
    __builtin_amdgcn_s_setprio(0);
#pragma unroll
    for (int p = 0; p < 2; ++p) {
      int key = p * 32 + (tid >> 3);
      int d0 = (tid & 7) * 8;
      s16x8 vrow = *(const s16x8*)&Vb[(size_t)(kv0 + key) * RS + d0];
#pragma unroll
      for (int j = 0; j < 8; ++j) {
        int d = d0 + j;
        int byt = (d * 128 + key * 2) ^ ((d & 7) << 4);
        *(u16*)((char*)Vt + byt) = (u16)vrow[j];
      }
    }
    float p4[4][4];
    float tmax[4] = {-INFINITY, -INFINITY, -INFINITY, -INFINITY};
    int qr_base = q0 + w * 16 + g * 4;
#pragma unroll
    for (int t = 0; t < 4; ++t) {
      int key = kv0 + t * 16 + lr;
#pragma unroll
      for (int r = 0; r < 4; ++r) {
        float s = sc[t][r] * 0.125f;
        s = (key <= qr_base + r) ? s : -1e30f;
        p4[t][r] = s;
        tmax[r] = fmaxf(tmax[r], s);
      }
    }
#pragma unroll
    for (int off = 1; off < 16; off <<= 1)
#pragma unroll
      for (int r = 0; r < 4; ++r) tmax[r] = fmaxf(tmax[r], __shfl_xor(tmax[r], off, 64));
    float corr[4], rsum[4];
#pragma unroll
    for (int r = 0; r < 4; ++r) {
      float mn = fmaxf(mr[r], tmax[r]);
      corr[r] = __expf(mr[r] - mn);
      mr[r] = mn;
      rsum[r] = 0.f;
    }
#pragma unroll
    for (int t = 0; t < 4; ++t)
#pragma unroll
      for (int r = 0; r < 4; ++r) {
        float e = __expf(p4[t][r] - mr[r]);
        p4[t][r] = e;
        rsum[r] += e;
      }
#pragma unroll
    for (int off = 1; off < 16; off <<= 1)
#pragma unroll
      for (int r = 0; r < 4; ++r) rsum[r] += __shfl_xor(rsum[r], off, 64);
#pragma unroll
    for (int r = 0; r < 4; ++r) ls[r] = ls[r] * corr[r] + rsum[r];
#pragma unroll
    for (int n = 0; n < 4; ++n)
#pragma unroll
      for (int r = 0; r < 4; ++r) o[n][r] *= corr[r];
#pragma unroll
    for (int t = 0; t < 4; ++t)
#pragma unroll
      for (int r = 0; r < 4; ++r) {
        int prow = g * 4 + r;
        int byt = (prow * 128 + (t * 16 + lr) * 2) ^ ((prow & 7) << 4);
        *(u16*)(Pw + byt) = f2bf(p4[t][r]);
      }
    __syncthreads();
    __builtin_amdgcn_s_setprio(1);
#pragma unroll
    for (int ks = 0; ks < 2; ++ks) {
      int ab = (lr * 128 + ks * 64 + g * 16) ^ ((lr & 7) << 4);
      s16x8 pa = *(const s16x8*)(Pw + ab);
#pragma unroll
      for (int n = 0; n < 4; ++n) {
        int vb2 = ((n * 16 + lr) * 128 + ks * 64 + g * 16) ^ ((lr & 7) << 4);
        s16x8 vfr = *(const s16x8*)((const char*)Vt + vb2);
        o[n] = mfma16(pa, vfr, o[n]);
      }
    }
    __builtin_amdgcn_s_setprio(0);
    __syncthreads();
  }
#pragma unroll
  for (int n = 0; n < 4; ++n)
#pragma unroll
    for (int r = 0; r < 4; ++r) {
      float v = o[n][r] / ls[r];
      outp[(size_t)(b * 1024 + q0 + w * 16 + g * 4 + r) * 1024 + h * 64 + n * 16 + lr] = f2bf(v);
    }
}

// ---------------- launch ----------------
extern "C" void kernel_launch(void* const* d_in, const int* in_sizes, int n_in,
                              void* d_out, int out_size, void* d_ws, size_t ws_size,
                              hipStream_t stream)
{
  const int*   tokens = (const int*)  d_in[0];
  const float* embW   = (const float*)d_in[1];
  const float* Wq     = (const float*)d_in[2];
  const float* bq     = (const float*)d_in[3];
  const float* Wk     = (const float*)d_in[4];
  const float* bk     = (const float*)d_in[5];
  const float* Wv     = (const float*)d_in[6];
  const float* bv     = (const float*)d_in[7];
  const float* Wo     = (const float*)d_in[8];
  const float* bo     = (const float*)d_in[9];
  const float* ln1g   = (const float*)d_in[10];
  const float* ln1b   = (const float*)d_in[11];
  const float* ln2g   = (const float*)d_in[12];
  const float* ln2b   = (const float*)d_in[13];
  const float* W1     = (const float*)d_in[14];
  const float* b1     = (const float*)d_in[15];
  const float* W2     = (const float*)d_in[16];
  const float* b2     = (const float*)d_in[17];
  const float* lnfg   = (const float*)d_in[18];
  const float* lnfb   = (const float*)d_in[19];
  const float* headW  = (const float*)d_in[20];
  const float* headb  = (const float*)d_in[21];
  (void)in_sizes; (void)n_in; (void)out_size;

  char* ws = (char*)d_ws;
  u16*   qkvT = (u16*)(ws);               // [8][3072][1024] bf16
  u16*   woT  = (u16*)(ws + 50331648);    // [8][1024][1024]
  u16*   w1T  = (u16*)(ws + 67108864);    // [8][4096][1024]
  u16*   w2T  = (u16*)(ws + 134217728);   // [8][1024][4096]
  u16*   headT= (u16*)(ws + 201326592);   // [32000][1024]
  float* bqkv = (float*)(ws + 266862592); // [8][3072]
  float* x    = (float*)(ws + 266960896); // [4096][1024] f32 residual stream
  u16*   y    = (u16*)(ws + 283738112);   // [4096][1024] bf16 LN output
  u16*   qkv  = (u16*)(ws + 292126720);   // [4096][3072] bf16
  u16*   attno= (u16*)(ws + 317292544);   // [4096][1024] bf16
  u16*   h1   = (u16*)(ws + 325681152);   // [4096][4096] bf16
  float* pbuf = (float*)(ws + 359235584); // [4][4096][1024] f32 (64MB, optional)
  if (ws_size < 359235584ull) return;     // base scratch requirement
  const bool splitk = (ws_size >= 426344448ull);  // + 64MB partials

  dim3 blk(256);
  dim3 blk5(512);
  // weight prep (transpose_cvt2: in rows = bx*64, in cols = by*32)
  transpose_cvt2<<<dim3(16, 32, 8),  blk, 0, stream>>>(Wq, qkvT,           1024,  1048576LL, 3145728LL, 1024);
  transpose_cvt2<<<dim3(16, 32, 8),  blk, 0, stream>>>(Wk, qkvT + 1048576, 1024,  1048576LL, 3145728LL, 1024);
  transpose_cvt2<<<dim3(16, 32, 8),  blk, 0, stream>>>(Wv, qkvT + 2097152, 1024,  1048576LL, 3145728LL, 1024);
  transpose_cvt2<<<dim3(16, 32, 8),  blk, 0, stream>>>(Wo, woT,            1024,  1048576LL, 1048576LL, 1024);
  transpose_cvt2<<<dim3(16, 128, 8), blk, 0, stream>>>(W1, w1T,            4096,  4194304LL, 4194304LL, 1024);
  transpose_cvt2<<<dim3(64, 32, 8),  blk, 0, stream>>>(W2, w2T,            1024,  4194304LL, 4194304LL, 4096);
  transpose_cvt2<<<dim3(16, 1000, 1),blk, 0, stream>>>(headW, headT,       32000, 0LL,       0LL,       1024);
  pack_bqkv<<<96, blk, 0, stream>>>(bq, bk, bv, bqkv);
  // embedding + first LN
  embed_kernel<<<4096, blk, 0, stream>>>(tokens, embW, x);
  ln_kernel<<<4096, blk, 0, stream>>>(x, ln1g, ln1b, y);
  // layers
  for (int ly = 0; ly < 8; ++ly) {
    // QKV: gy=16, gxp8=2, real gx=12 -> grid 256
    gemm256<0, 0, 0><<<256, blk5, 0, stream>>>(y, 1024,
        qkvT + (size_t)ly * 3145728, bqkv + ly * 3072, qkv,
        4096, 3072, 1024, 2, 12);
    attn_kernel<<<dim3(64, 16), blk, 0, stream>>>(qkv, attno);
    // Wo: gemm_p with fused residual (R14-proven; split-K loses here)
    gemm_p<1, 0><<<256, blk, 0, stream>>>(attno, woT + (size_t)ly * 1048576,
        bo + ly * 1024, x, x, 4096, 1024, 1024, 8);
    ln_kernel<<<4096, blk, 0, stream>>>(x, ln2g + ly * 1024, ln2b + ly * 1024, y);
    // FF1: gy=16, gxp8=2, real gx=16 -> grid 256
    gemm256<0, 1, 0><<<256, blk5, 0, stream>>>(y, 1024,
        w1T + (size_t)ly * 4194304, b1 + ly * 4096, h1,
        4096, 4096, 1024, 2, 16);
    const float* ng = (ly < 7) ? (ln1g + (ly + 1) * 1024) : lnfg;
    const float* nb = (ly < 7) ? (ln1b + (ly + 1) * 1024) : lnfb;
    if (splitk) {
      // FF2 split-K=4: klen=1024; partials then reduce + residual + next-LN
      gemm256<3, 0, 1><<<256, blk5, 0, stream>>>(h1, 4096,
          w2T + (size_t)ly * 4194304, nullptr, pbuf,
          4096, 1024, 1024, 0, 0);
      red_ln<<<4096, blk, 0, stream>>>(pbuf, b2 + ly * 1024, x, ng, nb, y);
    } else {
      gemm_p<1, 0><<<256, blk, 0, stream>>>(h1, w2T + (size_t)ly * 4194304,
          b2 + ly * 1024, x, x, 4096, 1024, 4096, 8);
      ln_kernel<<<4096, blk, 0, stream>>>(x, ng, nb, y);
    }
  }
  // head: gy=16, gxp8=16, real gx=125 -> grid 2048
  gemm256<2, 0, 0><<<2048, blk5, 0, stream>>>(y, 1024, headT, headb,
      (float*)d_out, 4096, 32000, 1024, 16, 125);
}

// Round 17
// 2300.652 us; speedup vs baseline: 1.0379x; 1.0379x over previous
//
#include <hip/hip_runtime.h>
#include <math.h>

// TransformerLanguageModel forward on MI355X (gfx950).
// R17: exact R14 restoration. R16-vs-R14 A/B isolated attn setprio as a
//      +89us regression: our attn is 4-wave barrier-lockstep per KV tile
//      (m190 regime: setprio hurts), NOT the independent-wave m191 regime.
//      Config: gemm256 (BK=64, ring-2, XCD super-tiles) for QKV/FF1/head;
//      gemm_p for Wo; FF2 split-K=4 + fused reduce+residual+LN; full-line
//      transpose_cvt2; fused embed/LN chain.

using u16 = unsigned short;
using u32 = unsigned int;
typedef __attribute__((ext_vector_type(4))) float  f32x4;
typedef __attribute__((ext_vector_type(8))) short  s16x8;
typedef __attribute__((ext_vector_type(8))) __bf16 bf16x8;

__device__ __forceinline__ u16 f2bf(float f) {
  u32 u = __builtin_bit_cast(u32, f);
  u += 0x7fffu + ((u >> 16) & 1u);   // round-to-nearest-even
  return (u16)(u >> 16);
}

__device__ __forceinline__ f32x4 mfma16(s16x8 a, s16x8 b, f32x4 c) {
  return __builtin_amdgcn_mfma_f32_16x16x32_bf16(
      __builtin_bit_cast(bf16x8, a), __builtin_bit_cast(bf16x8, b), c, 0, 0, 0);
}

#define GLD16(gp, lp) __builtin_amdgcn_global_load_lds(                    \
    (const __attribute__((address_space(1))) void*)(gp),                   \
    (__attribute__((address_space(3))) void*)(lp), 16, 0, 0)

// ---------------- weight transpose + f32->bf16 convert ----------------
// in tile: rows bx*64..+63, cols by*32..+31  ->  out[by*32+r][bx*64+c]
__global__ __launch_bounds__(256) void transpose_cvt2(
    const float* __restrict__ in, u16* __restrict__ out,
    int C, long long inLS, long long outLS, int outRS)
{
  __shared__ float t[32][65];
  int tid = threadIdx.x;
  const float* ip = in + (size_t)blockIdx.z * inLS +
                    ((size_t)blockIdx.x * 64) * C + blockIdx.y * 32;
#pragma unroll
  for (int it = 0; it < 8; ++it) {
    int idx = it * 256 + tid;
    int ir = idx >> 5, ic = idx & 31;
    t[ic][ir] = ip[(size_t)ir * C + ic];
  }
  __syncthreads();
  int r = tid >> 3, c0 = (tid & 7) * 8;
  u16* op = out + (size_t)blockIdx.z * outLS +
            ((size_t)blockIdx.y * 32 + r) * outRS + blockIdx.x * 64 + c0;
  const float* src = &t[r][c0];
  uint4 q;
  q.x = (u32)f2bf(src[0]) | ((u32)f2bf(src[1]) << 16);
  q.y = (u32)f2bf(src[2]) | ((u32)f2bf(src[3]) << 16);
  q.z = (u32)f2bf(src[4]) | ((u32)f2bf(src[5]) << 16);
  q.w = (u32)f2bf(src[6]) | ((u32)f2bf(src[7]) << 16);
  *(uint4*)op = q;
}

__global__ __launch_bounds__(256) void pack_bqkv(
    const float* __restrict__ bq, const float* __restrict__ bk,
    const float* __restrict__ bv, float* __restrict__ outb)
{
  int i = blockIdx.x * 256 + threadIdx.x;  // 8*3072 total
  int ly = i / 3072, j = i % 3072;
  float v = (j < 1024) ? bq[ly * 1024 + j]
          : (j < 2048) ? bk[ly * 1024 + (j - 1024)]
                       : bv[ly * 1024 + (j - 2048)];
  outb[i] = v;
}

// ---------------- embedding + positional encoding ----------------
__global__ __launch_bounds__(256) void embed_kernel(
    const int* __restrict__ tokens, const float* __restrict__ embW,
    float* __restrict__ x)
{
  int row = blockIdx.x;            // b*1024 + s
  int s = row & 1023;
  int tok = tokens[row];
  int d0 = threadIdx.x * 4;
  float4 e = *(const float4*)&embW[(size_t)tok * 1024 + d0];
  const float c = -9.210340371976184f / 1024.0f;  // -ln(10000)/D
  float div0 = expf((float)d0 * c);
  float div1 = expf((float)(d0 + 2) * c);
  float sn0, cs0, sn1, cs1;
  sincosf((float)s * div0, &sn0, &cs0);
  sincosf((float)s * div1, &sn1, &cs1);
  float4 r;
  r.x = e.x + sn0; r.y = e.y + cs0; r.z = e.z + sn1; r.w = e.w + cs1;
  *(float4*)&x[(size_t)row * 1024 + d0] = r;
}

// ---------------- layernorm (f32 in -> bf16 out) ----------------
__global__ __launch_bounds__(256) void ln_kernel(
    const float* __restrict__ x, const float* __restrict__ g,
    const float* __restrict__ b, u16* __restrict__ y)
{
  int row = blockIdx.x, tid = threadIdx.x;
  float4 v = *(const float4*)&x[(size_t)row * 1024 + tid * 4];
  float sum = v.x + v.y + v.z + v.w;
  float sq = v.x * v.x + v.y * v.y + v.z * v.z + v.w * v.w;
#pragma unroll
  for (int o = 32; o > 0; o >>= 1) {
    sum += __shfl_xor(sum, o, 64);
    sq  += __shfl_xor(sq,  o, 64);
  }
  __shared__ float ps[8];
  int w = tid >> 6;
  if ((tid & 63) == 0) { ps[w] = sum; ps[4 + w] = sq; }
  __syncthreads();
  sum = ps[0] + ps[1] + ps[2] + ps[3];
  sq  = ps[4] + ps[5] + ps[6] + ps[7];
  float mu = sum * (1.0f / 1024.0f);
  float var = sq * (1.0f / 1024.0f) - mu * mu;
  float rs = rsqrtf(var + 1e-5f);
  float4 gg = *(const float4*)&g[tid * 4];
  float4 bb = *(const float4*)&b[tid * 4];
  u32 lo = (u32)f2bf((v.x - mu) * rs * gg.x + bb.x) |
           ((u32)f2bf((v.y - mu) * rs * gg.y + bb.y) << 16);
  u32 hi = (u32)f2bf((v.z - mu) * rs * gg.z + bb.z) |
           ((u32)f2bf((v.w - mu) * rs * gg.w + bb.w) << 16);
  uint2 o2; o2.x = lo; o2.y = hi;
  *(uint2*)&y[(size_t)row * 1024 + tid * 4] = o2;
}

// ---------------- split-K reduce + residual + LayerNorm fused ----------
// x += p0+p1+p2+p3 + bias;  y = LN(x; g,b)
__global__ __launch_bounds__(256) void red_ln(
    const float* __restrict__ p, const float* __restrict__ bias,
    float* __restrict__ x, const float* __restrict__ g,
    const float* __restrict__ b, u16* __restrict__ y)
{
  int row = blockIdx.x, tid = threadIdx.x;
  size_t idx = (size_t)row * 1024 + tid * 4;
  f32x4 v  = *(f32x4*)&x[idx];
  v = v + *(const f32x4*)&p[idx]
        + *(const f32x4*)&p[idx + 4194304]
        + *(const f32x4*)&p[idx + 8388608]
        + *(const f32x4*)&p[idx + 12582912]
        + *(const f32x4*)&bias[tid * 4];
  *(f32x4*)&x[idx] = v;
  float sum = v.x + v.y + v.z + v.w;
  float sq  = v.x * v.x + v.y * v.y + v.z * v.z + v.w * v.w;
#pragma unroll
  for (int o = 32; o > 0; o >>= 1) {
    sum += __shfl_xor(sum, o, 64);
    sq  += __shfl_xor(sq,  o, 64);
  }
  __shared__ float ps[8];
  int w = tid >> 6;
  if ((tid & 63) == 0) { ps[w] = sum; ps[4 + w] = sq; }
  __syncthreads();
  sum = ps[0] + ps[1] + ps[2] + ps[3];
  sq  = ps[4] + ps[5] + ps[6] + ps[7];
  float mu = sum * (1.0f / 1024.0f);
  float var = sq * (1.0f / 1024.0f) - mu * mu;
  float rs = rsqrtf(var + 1e-5f);
  float4 gg = *(const float4*)&g[tid * 4];
  float4 bb = *(const float4*)&b[tid * 4];
  u32 lo = (u32)f2bf((v.x - mu) * rs * gg.x + bb.x) |
           ((u32)f2bf((v.y - mu) * rs * gg.y + bb.y) << 16);
  u32 hi = (u32)f2bf((v.z - mu) * rs * gg.z + bb.z) |
           ((u32)f2bf((v.w - mu) * rs * gg.w + bb.w) << 16);
  uint2 o2; o2.x = lo; o2.y = hi;
  *(uint2*)&y[idx] = o2;
}

// ---------------- GEMM 256x256, BK=64, 8 waves, ring-2, 1 barrier/K-tile -
// (R12-verified form.)  C[M,N] = A[M,K] @ Bt[N,K] + bias.
// OMODE 0: bf16 out; 2: f32 out; 3: f32 partial (no bias; Cp + split*M*N).
// MAP 0: 4x8 super-tiles per XCD.  MAP 1: split-K=4 (offset split*klen).
template<int OMODE, int RELU, int MAP>
__global__ __launch_bounds__(512, 2) void gemm256(
    const u16* __restrict__ A, int lda, const u16* __restrict__ Bt,
    const float* __restrict__ bias, void* Cp, int M, int N, int klen,
    int gxp8, int gxreal)
{
  __shared__ alignas(16) u16 lds[2][32768];
  const int tid = threadIdx.x;
  const int w = tid >> 6, l = tid & 63;
  const int g = l >> 4, lr = l & 15;
  const int wm = w >> 2, wn = w & 3;            // 2 x 4 waves, wave tile 128x64
  const int bid = blockIdx.x;
  const int xcd = bid & 7, k = bid >> 3;
  int by, bx, split = 0;
  if (MAP == 0) {
    int t = k >> 5, j = k & 31;
    int s = xcd + 8 * t;
    by = (s / gxp8) * 4 + (j & 3);
    bx = (s % gxp8) * 8 + (j >> 2);
    if (bx >= gxreal) return;
  } else {
    split = bid & 3;
    by = (bid >> 2) & 15;
    bx = bid >> 6;
  }
  const int m0 = by << 8, n0 = bx << 8;
  const u16* Ab = A  + (size_t)split * klen;    // K-offset for split-K
  const u16* Bb = Bt + (size_t)split * klen;

  // staging: 4 x 16B for A and 4 x 16B for B per thread per K-tile.
  const u16* Ag[4]; const u16* Bg[4]; int dstE[4];
#pragma unroll
  for (int s2 = 0; s2 < 4; ++s2) {
    int idx = s2 * 512 + tid;
    int row = idx >> 3;
    int ch = (idx & 7) ^ (row & 7);             // involutive chunk swizzle
    Ag[s2] = Ab + (size_t)(m0 + row) * lda + ch * 8;
    Bg[s2] = Bb + (size_t)(n0 + row) * lda + ch * 8;
    dstE[s2] = idx * 8;
  }
  // fragment reads: logical chunk (ks*4+g) at physical (ks*4+g)^(lr&7)
  const int colx0 = ((g)     ^ (lr & 7)) * 8;   // ks=0
  const int colx1 = ((4 + g) ^ (lr & 7)) * 8;   // ks=1
  const int abase = (wm * 128 + lr) * 64;           // + mf*1024 + colx
  const int bbase = 16384 + (wn * 64 + lr) * 64;    // + nf*1024 + colx

  f32x4 acc[8][4];
#pragma unroll
  for (int i = 0; i < 8; ++i)
#pragma unroll
    for (int j2 = 0; j2 < 4; ++j2) acc[i][j2] = f32x4{0.f, 0.f, 0.f, 0.f};

  const int nk = klen >> 6;
  // prologue: stage tile 0
#pragma unroll
  for (int s2 = 0; s2 < 4; ++s2) GLD16(Ag[s2], &lds[0][dstE[s2]]);
#pragma unroll
  for (int s2 = 0; s2 < 4; ++s2) GLD16(Bg[s2], &lds[0][16384 + dstE[s2]]);
  asm volatile("s_waitcnt vmcnt(0)" ::: "memory");   // my tile-0 loads landed
  __builtin_amdgcn_s_barrier();                      // => ALL waves' landed (R4 rule)

  int cur = 0;
  for (int t = 0; t < nk; ++t) {
    const bool more = (t + 1 < nk);
    // next-tile GLDs first (max in-flight time). Overwrites lds[cur^1] =
    // tile t-1: all waves' reads of it completed before their iter-(t-1)
    // MFMA, hence before the iter-(t-1) barrier (R6-proven).
    if (more) {
      const int kn = (t + 1) << 6;
#pragma unroll
      for (int s2 = 0; s2 < 4; ++s2) GLD16(Ag[s2] + kn, &lds[cur ^ 1][dstE[s2]]);
#pragma unroll
      for (int s2 = 0; s2 < 4; ++s2) GLD16(Bg[s2] + kn, &lds[cur ^ 1][16384 + dstE[s2]]);
    }
    s16x8 a0[8], b0[4], a1[8], b1[4];
#pragma unroll
    for (int mf = 0; mf < 8; ++mf) a0[mf] = *(const s16x8*)&lds[cur][abase + mf * 1024 + colx0];
#pragma unroll
    for (int nf = 0; nf < 4; ++nf) b0[nf] = *(const s16x8*)&lds[cur][bbase + nf * 1024 + colx0];
#pragma unroll
    for (int mf = 0; mf < 8; ++mf) a1[mf] = *(const s16x8*)&lds[cur][abase + mf * 1024 + colx1];
#pragma unroll
    for (int nf = 0; nf < 4; ++nf) b1[nf] = *(const s16x8*)&lds[cur][bbase + nf * 1024 + colx1];
    __builtin_amdgcn_s_setprio(1);
#pragma unroll
    for (int mf = 0; mf < 8; ++mf)
#pragma unroll
      for (int nf = 0; nf < 4; ++nf) acc[mf][nf] = mfma16(a0[mf], b0[nf], acc[mf][nf]);
#pragma unroll
    for (int mf = 0; mf < 8; ++mf)
#pragma unroll
      for (int nf = 0; nf < 4; ++nf) acc[mf][nf] = mfma16(a1[mf], b1[nf], acc[mf][nf]);
    __builtin_amdgcn_s_setprio(0);
    if (more) {
      asm volatile("s_waitcnt vmcnt(0)" ::: "memory");
      __builtin_amdgcn_s_barrier();
      cur ^= 1;
    }
  }

  // ---- epilogue: LDS-staged, full-cache-line vectorized stores (R8) ----
  float* fst = (float*)(void*)&lds[0][0];
  float* Cf = (OMODE == 3)
            ? ((float*)Cp + (size_t)split * ((size_t)M * N))
            : (float*)Cp;
#pragma unroll
  for (int mf = 0; mf < 8; ++mf) {
    __builtin_amdgcn_s_barrier();        // prior round's LDS reads complete
#pragma unroll
    for (int nf = 0; nf < 4; ++nf) {
      int cl = wn * 64 + nf * 16 + lr;
      float bv = 0.f;
      if (OMODE != 3) bv = bias[n0 + cl];
      int rl = wm * 16 + g * 4;
#pragma unroll
      for (int r = 0; r < 4; ++r) {
        float v = acc[mf][nf][r] + bv;
        if (RELU) v = fmaxf(v, 0.f);
        fst[(rl + r) * 260 + cl] = v;    // banks: 2-way (free)
      }
    }
    __builtin_amdgcn_s_barrier();
    if (OMODE == 0) {
      // 32 rows x 256 bf16 = 1024 segs of 16B
#pragma unroll
      for (int it = 0; it < 2; ++it) {
        int seg = it * 512 + tid;
        int row = seg >> 5;
        int co  = (seg & 31) * 8;
        int grow = m0 + (row >> 4) * 128 + mf * 16 + (row & 15);
        const float* src = &fst[row * 260 + co];
        uint4 q;
        q.x = (u32)f2bf(src[0]) | ((u32)f2bf(src[1]) << 16);
        q.y = (u32)f2bf(src[2]) | ((u32)f2bf(src[3]) << 16);
        q.z = (u32)f2bf(src[4]) | ((u32)f2bf(src[5]) << 16);
        q.w = (u32)f2bf(src[6]) | ((u32)f2bf(src[7]) << 16);
        *(uint4*)&((u16*)Cp)[(size_t)grow * N + n0 + co] = q;
      }
    } else {
      // 32 rows x 256 f32 = 2048 segs of 16B
#pragma unroll
      for (int it = 0; it < 4; ++it) {
        int seg = it * 512 + tid;
        int row = seg >> 6;
        int co  = (seg & 63) * 4;
        int grow = m0 + (row >> 4) * 128 + mf * 16 + (row & 15);
        f32x4 q = *(const f32x4*)&fst[row * 260 + co];
        *(f32x4*)&Cf[(size_t)grow * N + n0 + co] = q;
      }
    }
  }
}

// ---------------- GEMM 128x128, 4 waves, ring-2, 1 barrier/K-tile --------
// For N=1024 shapes (Wo, FF2 fallback). OMODE 1: f32 out + residual add.
template<int OMODE, int RELU>
__global__ __launch_bounds__(256, 3) void gemm_p(
    const u16* __restrict__ A, const u16* __restrict__ Bt,
    const float* __restrict__ bias, const float* res, void* Cp,
    int M, int N, int K, int gx)
{
  __shared__ alignas(16) u16 lds[2][8192];
  const int tid = threadIdx.x;
  const int w = tid >> 6, l = tid & 63;
  const int g = l >> 4, lr = l & 15;
  const int wm = w >> 1, wn = w & 1;
  int nwg = gridDim.x;
  int bid = blockIdx.x;
  int swz = (bid & 7) * (nwg >> 3) + (bid >> 3);
  int bx = swz % gx, by = swz / gx;
  int m0 = by << 7, n0 = bx << 7;

  const u16 *Ag[2], *Bg[2];
  int dstA[2], dstB[2];
#pragma unroll
  for (int s = 0; s < 2; ++s) {
    int idx = s * 256 + tid;
    int row = idx >> 2;
    int ch = (idx & 3) ^ ((row >> 1) & 3);
    Ag[s] = A  + (size_t)(m0 + row) * K + ch * 8;
    Bg[s] = Bt + (size_t)(n0 + row) * K + ch * 8;
    dstA[s] = idx * 8;
    dstB[s] = 4096 + idx * 8;
  }
  const int colx = (g ^ ((lr >> 1) & 3)) * 8;
  const int aoff = (wm * 64 + lr) * 32 + colx;
  const int boff = 4096 + (wn * 64 + lr) * 32 + colx;

  f32x4 acc[4][4];
#pragma unroll
  for (int i = 0; i < 4; ++i)
#pragma unroll
    for (int j = 0; j < 4; ++j) acc[i][j] = f32x4{0.f, 0.f, 0.f, 0.f};

  const int nk = K >> 5;
#pragma unroll
  for (int s = 0; s < 2; ++s) GLD16(Ag[s], &lds[0][dstA[s]]);
#pragma unroll
  for (int s = 0; s < 2; ++s) GLD16(Bg[s], &lds[0][dstB[s]]);
  asm volatile("s_waitcnt vmcnt(0)" ::: "memory");
  __builtin_amdgcn_s_barrier();

  int cur = 0;
  s16x8 aC[4], bC[4];
#pragma unroll
  for (int i = 0; i < 4; ++i) aC[i] = *(const s16x8*)&lds[0][aoff + i * 512];
#pragma unroll
  for (int j = 0; j < 4; ++j) bC[j] = *(const s16x8*)&lds[0][boff + j * 512];

  for (int t = 0; t < nk; ++t) {
    const bool more = (t + 1 < nk);
    if (more) {
      const int kn = (t + 1) << 5;
#pragma unroll
      for (int s = 0; s < 2; ++s) GLD16(Ag[s] + kn, &lds[cur ^ 1][dstA[s]]);
#pragma unroll
      for (int s = 0; s < 2; ++s) GLD16(Bg[s] + kn, &lds[cur ^ 1][dstB[s]]);
    }
    __builtin_amdgcn_s_setprio(1);
#pragma unroll
    for (int i = 0; i < 4; ++i)
#pragma unroll
      for (int j = 0; j < 4; ++j) acc[i][j] = mfma16(aC[i], bC[j], acc[i][j]);
    __builtin_amdgcn_s_setprio(0);
    if (more) {
      asm volatile("s_waitcnt vmcnt(0)" ::: "memory");
      __builtin_amdgcn_s_barrier();
      cur ^= 1;
#pragma unroll
      for (int i = 0; i < 4; ++i) aC[i] = *(const s16x8*)&lds[cur][aoff + i * 512];
#pragma unroll
      for (int j = 0; j < 4; ++j) bC[j] = *(const s16x8*)&lds[cur][boff + j * 512];
    }
  }
#pragma unroll
  for (int mf = 0; mf < 4; ++mf) {
    int row = m0 + wm * 64 + mf * 16 + g * 4;
#pragma unroll
    for (int nf = 0; nf < 4; ++nf) {
      int col = n0 + wn * 64 + nf * 16 + lr;
      float bv = bias[col];
#pragma unroll
      for (int r = 0; r < 4; ++r) {
        float v = acc[mf][nf][r] + bv;
        if (RELU) v = fmaxf(v, 0.f);
        size_t idx = (size_t)(row + r) * N + col;
        if (OMODE == 0)      ((u16*)Cp)[idx] = f2bf(v);
        else if (OMODE == 1) ((float*)Cp)[idx] = v + res[idx];
        else                 ((float*)Cp)[idx] = v;
      }
    }
  }
}

// ---------------- flash attention (R14 form: no setprio) ----------------
__global__ __launch_bounds__(256) void attn_kernel(
    const u16* __restrict__ qkv, u16* __restrict__ outp)
{
  int b = blockIdx.x >> 4, h = blockIdx.x & 15;
  int q0 = blockIdx.y << 6;
  int tid = threadIdx.x, w = tid >> 6, l = tid & 63;
  int g = l >> 4, lr = l & 15;
  const int RS = 3072;
  const u16* base = qkv + (size_t)b * 1024 * RS + h * 64;
  const u16* Qb = base;
  const u16* Kb = base + 1024;
  const u16* Vb = base + 2048;
  __shared__ alignas(16) u16 Plds[4][1024];
  __shared__ alignas(16) u16 Vt[4096];
  char* Pw = (char*)&Plds[w][0];

  s16x8 qf[2];
#pragma unroll
  for (int ks = 0; ks < 2; ++ks)
    qf[ks] = *(const s16x8*)&Qb[(size_t)(q0 + w * 16 + lr) * RS + ks * 32 + g * 8];

  f32x4 o[4];
#pragma unroll
  for (int n = 0; n < 4; ++n) o[n] = f32x4{0.f, 0.f, 0.f, 0.f};
  float mr[4] = {-INFINITY, -INFINITY, -INFINITY, -INFINITY};
  float ls[4] = {0.f, 0.f, 0.f, 0.f};

  int ntile = (q0 >> 6) + 1;
  for (int kt = 0; kt < ntile; ++kt) {
    int kv0 = kt << 6;
    f32x4 sc[4];
#pragma unroll
    for (int t = 0; t < 4; ++t) sc[t] = f32x4{0.f, 0.f, 0.f, 0.f};
#pragma unroll
    for (int ks = 0; ks < 2; ++ks)
#pragma unroll
      for (int t = 0; t < 4; ++t) {
        s16x8 kf = *(const s16x8*)&Kb[(size_t)(kv0 + t * 16 + lr) * RS + ks * 32 + g * 8];
        sc[t] = mfma16(qf[ks], kf, sc[t]);
      }
#pragma unroll
    for (int p = 0; p < 2; ++p) {
      int key = p * 32 + (tid >> 3);
      int d0 = (tid & 7) * 8;
      s16x8 vrow = *(const s16x8*)&Vb[(size_t)(kv0 + key) * RS + d0];
#pragma unroll
      for (int j = 0; j < 8; ++j) {
        int d = d0 + j;
        int byt = (d * 128 + key * 2) ^ ((d & 7) << 4);
        *(u16*)((char*)Vt + byt) = (u16)vrow[j];
      }
    }
    float p4[4][4];
    float tmax[4] = {-INFINITY, -INFINITY, -INFINITY, -INFINITY};
    int qr_base = q0 + w * 16 + g * 4;
#pragma unroll
    for (int t = 0; t < 4; ++t) {
      int key = kv0 + t * 16 + lr;
#pragma unroll
      for (int r = 0; r < 4; ++r) {
        float s = sc[t][r] * 0.125f;
        s = (key <= qr_base + r) ? s : -1e30f;
        p4[t][r] = s;
        tmax[r] = fmaxf(tmax[r], s);
      }
    }
#pragma unroll
    for (int off = 1; off < 16; off <<= 1)
#pragma unroll
      for (int r = 0; r < 4; ++r) tmax[r] = fmaxf(tmax[r], __shfl_xor(tmax[r], off, 64));
    float corr[4], rsum[4];
#pragma unroll
    for (int r = 0; r < 4; ++r) {
      float mn = fmaxf(mr[r], tmax[r]);
      corr[r] = __expf(mr[r] - mn);
      mr[r] = mn;
      rsum[r] = 0.f;
    }
#pragma unroll
    for (int t = 0; t < 4; ++t)
#pragma unroll
      for (int r = 0; r < 4; ++r) {
        float e = __expf(p4[t][r] - mr[r]);
        p4[t][r] = e;
        rsum[r] += e;
      }
#pragma unroll
    for (int off = 1; off < 16; off <<= 1)
#pragma unroll
      for (int r = 0; r < 4; ++r) rsum[r] += __shfl_xor(rsum[r], off, 64);
#pragma unroll
    for (int r = 0; r < 4; ++r) ls[r] = ls[r] * corr[r] + rsum[r];
#pragma unroll
    for (int n = 0; n < 4; ++n)
#pragma unroll
      for (int r = 0; r < 4; ++r) o[n][r] *= corr[r];
#pragma unroll
    for (int t = 0; t < 4; ++t)
#pragma unroll
      for (int r = 0; r < 4; ++r) {
        int prow = g * 4 + r;
        int byt = (prow * 128 + (t * 16 + lr) * 2) ^ ((prow & 7) << 4);
        *(u16*)(Pw + byt) = f2bf(p4[t][r]);
      }
    __syncthreads();
#pragma unroll
    for (int ks = 0; ks < 2; ++ks) {
      int ab = (lr * 128 + ks * 64 + g * 16) ^ ((lr & 7) << 4);
      s16x8 pa = *(const s16x8*)(Pw + ab);
#pragma unroll
      for (int n = 0; n < 4; ++n) {
        int vb2 = ((n * 16 + lr) * 128 + ks * 64 + g * 16) ^ ((lr & 7) << 4);
        s16x8 vfr = *(const s16x8*)((const char*)Vt + vb2);
        o[n] = mfma16(pa, vfr, o[n]);
      }
    }
    __syncthreads();
  }
#pragma unroll
  for (int n = 0; n < 4; ++n)
#pragma unroll
    for (int r = 0; r < 4; ++r) {
      float v = o[n][r] / ls[r];
      outp[(size_t)(b * 1024 + q0 + w * 16 + g * 4 + r) * 1024 + h * 64 + n * 16 + lr] = f2bf(v);
    }
}

// ---------------- launch ----------------
extern "C" void kernel_launch(void* const* d_in, const int* in_sizes, int n_in,
                              void* d_out, int out_size, void* d_ws, size_t ws_size,
                              hipStream_t stream)
{
  const int*   tokens = (const int*)  d_in[0];
  const float* embW   = (const float*)d_in[1];
  const float* Wq     = (const float*)d_in[2];
  const float* bq     = (const float*)d_in[3];
  const float* Wk     = (const float*)d_in[4];
  const float* bk     = (const float*)d_in[5];
  const float* Wv     = (const float*)d_in[6];
  const float* bv     = (const float*)d_in[7];
  const float* Wo     = (const float*)d_in[8];
  const float* bo     = (const float*)d_in[9];
  const float* ln1g   = (const float*)d_in[10];
  const float* ln1b   = (const float*)d_in[11];
  const float* ln2g   = (const float*)d_in[12];
  const float* ln2b   = (const float*)d_in[13];
  const float* W1     = (const float*)d_in[14];
  const float* b1     = (const float*)d_in[15];
  const float* W2     = (const float*)d_in[16];
  const float* b2     = (const float*)d_in[17];
  const float* lnfg   = (const float*)d_in[18];
  const float* lnfb   = (const float*)d_in[19];
  const float* headW  = (const float*)d_in[20];
  const float* headb  = (const float*)d_in[21];
  (void)in_sizes; (void)n_in; (void)out_size;

  char* ws = (char*)d_ws;
  u16*   qkvT = (u16*)(ws);               // [8][3072][1024] bf16
  u16*   woT  = (u16*)(ws + 50331648);    // [8][1024][1024]
  u16*   w1T  = (u16*)(ws + 67108864);    // [8][4096][1024]
  u16*   w2T  = (u16*)(ws + 134217728);   // [8][1024][4096]
  u16*   headT= (u16*)(ws + 201326592);   // [32000][1024]
  float* bqkv = (float*)(ws + 266862592); // [8][3072]
  float* x    = (float*)(ws + 266960896); // [4096][1024] f32 residual stream
  u16*   y    = (u16*)(ws + 283738112);   // [4096][1024] bf16 LN output
  u16*   qkv  = (u16*)(ws + 292126720);   // [4096][3072] bf16
  u16*   attno= (u16*)(ws + 317292544);   // [4096][1024] bf16
  u16*   h1   = (u16*)(ws + 325681152);   // [4096][4096] bf16
  float* pbuf = (float*)(ws + 359235584); // [4][4096][1024] f32 (64MB, optional)
  if (ws_size < 359235584ull) return;     // base scratch requirement
  const bool splitk = (ws_size >= 426344448ull);  // + 64MB partials

  dim3 blk(256);
  dim3 blk5(512);
  // weight prep (transpose_cvt2: in rows = bx*64, in cols = by*32)
  transpose_cvt2<<<dim3(16, 32, 8),  blk, 0, stream>>>(Wq, qkvT,           1024,  1048576LL, 3145728LL, 1024);
  transpose_cvt2<<<dim3(16, 32, 8),  blk, 0, stream>>>(Wk, qkvT + 1048576, 1024,  1048576LL, 3145728LL, 1024);
  transpose_cvt2<<<dim3(16, 32, 8),  blk, 0, stream>>>(Wv, qkvT + 2097152, 1024,  1048576LL, 3145728LL, 1024);
  transpose_cvt2<<<dim3(16, 32, 8),  blk, 0, stream>>>(Wo, woT,            1024,  1048576LL, 1048576LL, 1024);
  transpose_cvt2<<<dim3(16, 128, 8), blk, 0, stream>>>(W1, w1T,            4096,  4194304LL, 4194304LL, 1024);
  transpose_cvt2<<<dim3(64, 32, 8),  blk, 0, stream>>>(W2, w2T,            1024,  4194304LL, 4194304LL, 4096);
  transpose_cvt2<<<dim3(16, 1000, 1),blk, 0, stream>>>(headW, headT,       32000, 0LL,       0LL,       1024);
  pack_bqkv<<<96, blk, 0, stream>>>(bq, bk, bv, bqkv);
  // embedding + first LN
  embed_kernel<<<4096, blk, 0, stream>>>(tokens, embW, x);
  ln_kernel<<<4096, blk, 0, stream>>>(x, ln1g, ln1b, y);
  // layers
  for (int ly = 0; ly < 8; ++ly) {
    // QKV: gy=16, gxp8=2, real gx=12 -> grid 256
    gemm256<0, 0, 0><<<256, blk5, 0, stream>>>(y, 1024,
        qkvT + (size_t)ly * 3145728, bqkv + ly * 3072, qkv,
        4096, 3072, 1024, 2, 12);
    attn_kernel<<<dim3(64, 16), blk, 0, stream>>>(qkv, attno);
    // Wo: gemm_p with fused residual (R14-proven; split-K loses here)
    gemm_p<1, 0><<<256, blk, 0, stream>>>(attno, woT + (size_t)ly * 1048576,
        bo + ly * 1024, x, x, 4096, 1024, 1024, 8);
    ln_kernel<<<4096, blk, 0, stream>>>(x, ln2g + ly * 1024, ln2b + ly * 1024, y);
    // FF1: gy=16, gxp8=2, real gx=16 -> grid 256
    gemm256<0, 1, 0><<<256, blk5, 0, stream>>>(y, 1024,
        w1T + (size_t)ly * 4194304, b1 + ly * 4096, h1,
        4096, 4096, 1024, 2, 16);
    const float* ng = (ly < 7) ? (ln1g + (ly + 1) * 1024) : lnfg;
    const float* nb = (ly < 7) ? (ln1b + (ly + 1) * 1024) : lnfb;
    if (splitk) {
      // FF2 split-K=4: klen=1024; partials then reduce + residual + next-LN
      gemm256<3, 0, 1><<<256, blk5, 0, stream>>>(h1, 4096,
          w2T + (size_t)ly * 4194304, nullptr, pbuf,
          4096, 1024, 1024, 0, 0);
      red_ln<<<4096, blk, 0, stream>>>(pbuf, b2 + ly * 1024, x, ng, nb, y);
    } else {
      gemm_p<1, 0><<<256, blk, 0, stream>>>(h1, w2T + (size_t)ly * 4194304,
          b2 + ly * 1024, x, x, 4096, 1024, 4096, 8);
      ln_kernel<<<4096, blk, 0, stream>>>(x, ng, nb, y);
    }
  }
  // head: gy=16, gxp8=16, real gx=125 -> grid 2048
  gemm256<2, 0, 0><<<2048, blk5, 0, stream>>>(y, 1024, headT, headb,
      (float*)d_out, 4096, 32000, 1024, 16, 125);
}

// Round 18
// 2238.330 us; speedup vs baseline: 1.0668x; 1.0278x over previous
//
#include <hip/hip_runtime.h>
#include <math.h>

// TransformerLanguageModel forward on MI355X (gfx950).
// R18 = R17 (best-known: 2300us) + FF2 split-K partials stored in f16
//       (halves the 1GB/run partial round-trip; f16 partial magnitudes
//       ~0.07, rel err 5e-4 -> absolute ~3e-5, negligible vs 0.023 absmax).
// Config: gemm256 (BK=64, ring-2, XCD super-tiles) for QKV/FF1/head;
//         gemm_p for Wo; FF2 split-K=4 (f16 partials) + fused
//         reduce+residual+LN; full-line transpose_cvt2; no attn setprio
//         (R16/R17 A/B: lockstep regime, setprio costs +89us).

using u16 = unsigned short;
using u32 = unsigned int;
typedef __attribute__((ext_vector_type(4))) float     f32x4;
typedef __attribute__((ext_vector_type(8))) short     s16x8;
typedef __attribute__((ext_vector_type(8))) __bf16    bf16x8;
typedef __attribute__((ext_vector_type(4))) _Float16  f16x4;

__device__ __forceinline__ u16 f2bf(float f) {
  u32 u = __builtin_bit_cast(u32, f);
  u += 0x7fffu + ((u >> 16) & 1u);   // round-to-nearest-even
  return (u16)(u >> 16);
}

__device__ __forceinline__ u16 f2h(float f) {
  _Float16 h = (_Float16)f;
  return __builtin_bit_cast(u16, h);
}

__device__ __forceinline__ f32x4 mfma16(s16x8 a, s16x8 b, f32x4 c) {
  return __builtin_amdgcn_mfma_f32_16x16x32_bf16(
      __builtin_bit_cast(bf16x8, a), __builtin_bit_cast(bf16x8, b), c, 0, 0, 0);
}

#define GLD16(gp, lp) __builtin_amdgcn_global_load_lds(                    \
    (const __attribute__((address_space(1))) void*)(gp),                   \
    (__attribute__((address_space(3))) void*)(lp), 16, 0, 0)

// ---------------- weight transpose + f32->bf16 convert ----------------
// in tile: rows bx*64..+63, cols by*32..+31  ->  out[by*32+r][bx*64+c]
__global__ __launch_bounds__(256) void transpose_cvt2(
    const float* __restrict__ in, u16* __restrict__ out,
    int C, long long inLS, long long outLS, int outRS)
{
  __shared__ float t[32][65];
  int tid = threadIdx.x;
  const float* ip = in + (size_t)blockIdx.z * inLS +
                    ((size_t)blockIdx.x * 64) * C + blockIdx.y * 32;
#pragma unroll
  for (int it = 0; it < 8; ++it) {
    int idx = it * 256 + tid;
    int ir = idx >> 5, ic = idx & 31;
    t[ic][ir] = ip[(size_t)ir * C + ic];
  }
  __syncthreads();
  int r = tid >> 3, c0 = (tid & 7) * 8;
  u16* op = out + (size_t)blockIdx.z * outLS +
            ((size_t)blockIdx.y * 32 + r) * outRS + blockIdx.x * 64 + c0;
  const float* src = &t[r][c0];
  uint4 q;
  q.x = (u32)f2bf(src[0]) | ((u32)f2bf(src[1]) << 16);
  q.y = (u32)f2bf(src[2]) | ((u32)f2bf(src[3]) << 16);
  q.z = (u32)f2bf(src[4]) | ((u32)f2bf(src[5]) << 16);
  q.w = (u32)f2bf(src[6]) | ((u32)f2bf(src[7]) << 16);
  *(uint4*)op = q;
}

__global__ __launch_bounds__(256) void pack_bqkv(
    const float* __restrict__ bq, const float* __restrict__ bk,
    const float* __restrict__ bv, float* __restrict__ outb)
{
  int i = blockIdx.x * 256 + threadIdx.x;  // 8*3072 total
  int ly = i / 3072, j = i % 3072;
  float v = (j < 1024) ? bq[ly * 1024 + j]
          : (j < 2048) ? bk[ly * 1024 + (j - 1024)]
                       : bv[ly * 1024 + (j - 2048)];
  outb[i] = v;
}

// ---------------- embedding + positional encoding ----------------
__global__ __launch_bounds__(256) void embed_kernel(
    const int* __restrict__ tokens, const float* __restrict__ embW,
    float* __restrict__ x)
{
  int row = blockIdx.x;            // b*1024 + s
  int s = row & 1023;
  int tok = tokens[row];
  int d0 = threadIdx.x * 4;
  float4 e = *(const float4*)&embW[(size_t)tok * 1024 + d0];
  const float c = -9.210340371976184f / 1024.0f;  // -ln(10000)/D
  float div0 = expf((float)d0 * c);
  float div1 = expf((float)(d0 + 2) * c);
  float sn0, cs0, sn1, cs1;
  sincosf((float)s * div0, &sn0, &cs0);
  sincosf((float)s * div1, &sn1, &cs1);
  float4 r;
  r.x = e.x + sn0; r.y = e.y + cs0; r.z = e.z + sn1; r.w = e.w + cs1;
  *(float4*)&x[(size_t)row * 1024 + d0] = r;
}

// ---------------- layernorm (f32 in -> bf16 out) ----------------
__global__ __launch_bounds__(256) void ln_kernel(
    const float* __restrict__ x, const float* __restrict__ g,
    const float* __restrict__ b, u16* __restrict__ y)
{
  int row = blockIdx.x, tid = threadIdx.x;
  float4 v = *(const float4*)&x[(size_t)row * 1024 + tid * 4];
  float sum = v.x + v.y + v.z + v.w;
  float sq = v.x * v.x + v.y * v.y + v.z * v.z + v.w * v.w;
#pragma unroll
  for (int o = 32; o > 0; o >>= 1) {
    sum += __shfl_xor(sum, o, 64);
    sq  += __shfl_xor(sq,  o, 64);
  }
  __shared__ float ps[8];
  int w = tid >> 6;
  if ((tid & 63) == 0) { ps[w] = sum; ps[4 + w] = sq; }
  __syncthreads();
  sum = ps[0] + ps[1] + ps[2] + ps[3];
  sq  = ps[4] + ps[5] + ps[6] + ps[7];
  float mu = sum * (1.0f / 1024.0f);
  float var = sq * (1.0f / 1024.0f) - mu * mu;
  float rs = rsqrtf(var + 1e-5f);
  float4 gg = *(const float4*)&g[tid * 4];
  float4 bb = *(const float4*)&b[tid * 4];
  u32 lo = (u32)f2bf((v.x - mu) * rs * gg.x + bb.x) |
           ((u32)f2bf((v.y - mu) * rs * gg.y + bb.y) << 16);
  u32 hi = (u32)f2bf((v.z - mu) * rs * gg.z + bb.z) |
           ((u32)f2bf((v.w - mu) * rs * gg.w + bb.w) << 16);
  uint2 o2; o2.x = lo; o2.y = hi;
  *(uint2*)&y[(size_t)row * 1024 + tid * 4] = o2;
}

// ---------------- split-K reduce (f16 partials) + residual + LN fused ---
// x += p0+p1+p2+p3 + bias;  y = LN(x; g,b).  p: f16, 4 streams of M*N.
__global__ __launch_bounds__(256) void red_ln(
    const u16* __restrict__ p, const float* __restrict__ bias,
    float* __restrict__ x, const float* __restrict__ g,
    const float* __restrict__ b, u16* __restrict__ y)
{
  int row = blockIdx.x, tid = threadIdx.x;
  size_t idx = (size_t)row * 1024 + tid * 4;
  f32x4 v  = *(f32x4*)&x[idx];
  f16x4 h0 = *(const f16x4*)&p[idx];
  f16x4 h1 = *(const f16x4*)&p[idx + 4194304];
  f16x4 h2 = *(const f16x4*)&p[idx + 8388608];
  f16x4 h3 = *(const f16x4*)&p[idx + 12582912];
  v = v + __builtin_convertvector(h0, f32x4)
        + __builtin_convertvector(h1, f32x4)
        + __builtin_convertvector(h2, f32x4)
        + __builtin_convertvector(h3, f32x4)
        + *(const f32x4*)&bias[tid * 4];
  *(f32x4*)&x[idx] = v;
  float sum = v.x + v.y + v.z + v.w;
  float sq  = v.x * v.x + v.y * v.y + v.z * v.z + v.w * v.w;
#pragma unroll
  for (int o = 32; o > 0; o >>= 1) {
    sum += __shfl_xor(sum, o, 64);
    sq  += __shfl_xor(sq,  o, 64);
  }
  __shared__ float ps[8];
  int w = tid >> 6;
  if ((tid & 63) == 0) { ps[w] = sum; ps[4 + w] = sq; }
  __syncthreads();
  sum = ps[0] + ps[1] + ps[2] + ps[3];
  sq  = ps[4] + ps[5] + ps[6] + ps[7];
  float mu = sum * (1.0f / 1024.0f);
  float var = sq * (1.0f / 1024.0f) - mu * mu;
  float rs = rsqrtf(var + 1e-5f);
  float4 gg = *(const float4*)&g[tid * 4];
  float4 bb = *(const float4*)&b[tid * 4];
  u32 lo = (u32)f2bf((v.x - mu) * rs * gg.x + bb.x) |
           ((u32)f2bf((v.y - mu) * rs * gg.y + bb.y) << 16);
  u32 hi = (u32)f2bf((v.z - mu) * rs * gg.z + bb.z) |
           ((u32)f2bf((v.w - mu) * rs * gg.w + bb.w) << 16);
  uint2 o2; o2.x = lo; o2.y = hi;
  *(uint2*)&y[idx] = o2;
}

// ---------------- GEMM 256x256, BK=64, 8 waves, ring-2, 1 barrier/K-tile -
// C[M,N] = A[M,K] @ Bt[N,K] + bias.
// OMODE 0: bf16 out; 2: f32 out; 4: f16 partial (no bias; Cp + split*M*N).
// MAP 0: 4x8 super-tiles per XCD.  MAP 1: split-K=4 (offset split*klen).
template<int OMODE, int RELU, int MAP>
__global__ __launch_bounds__(512, 2) void gemm256(
    const u16* __restrict__ A, int lda, const u16* __restrict__ Bt,
    const float* __restrict__ bias, void* Cp, int M, int N, int klen,
    int gxp8, int gxreal)
{
  __shared__ alignas(16) u16 lds[2][32768];
  const int tid = threadIdx.x;
  const int w = tid >> 6, l = tid & 63;
  const int g = l >> 4, lr = l & 15;
  const int wm = w >> 2, wn = w & 3;            // 2 x 4 waves, wave tile 128x64
  const int bid = blockIdx.x;
  const int xcd = bid & 7, k = bid >> 3;
  int by, bx, split = 0;
  if (MAP == 0) {
    int t = k >> 5, j = k & 31;
    int s = xcd + 8 * t;
    by = (s / gxp8) * 4 + (j & 3);
    bx = (s % gxp8) * 8 + (j >> 2);
    if (bx >= gxreal) return;
  } else {
    split = bid & 3;
    by = (bid >> 2) & 15;
    bx = bid >> 6;
  }
  const int m0 = by << 8, n0 = bx << 8;
  const u16* Ab = A  + (size_t)split * klen;    // K-offset for split-K
  const u16* Bb = Bt + (size_t)split * klen;

  // staging: 4 x 16B for A and 4 x 16B for B per thread per K-tile.
  const u16* Ag[4]; const u16* Bg[4]; int dstE[4];
#pragma unroll
  for (int s2 = 0; s2 < 4; ++s2) {
    int idx = s2 * 512 + tid;
    int row = idx >> 3;
    int ch = (idx & 7) ^ (row & 7);             // involutive chunk swizzle
    Ag[s2] = Ab + (size_t)(m0 + row) * lda + ch * 8;
    Bg[s2] = Bb + (size_t)(n0 + row) * lda + ch * 8;
    dstE[s2] = idx * 8;
  }
  // fragment reads: logical chunk (ks*4+g) at physical (ks*4+g)^(lr&7)
  const int colx0 = ((g)     ^ (lr & 7)) * 8;   // ks=0
  const int colx1 = ((4 + g) ^ (lr & 7)) * 8;   // ks=1
  const int abase = (wm * 128 + lr) * 64;           // + mf*1024 + colx
  const int bbase = 16384 + (wn * 64 + lr) * 64;    // + nf*1024 + colx

  f32x4 acc[8][4];
#pragma unroll
  for (int i = 0; i < 8; ++i)
#pragma unroll
    for (int j2 = 0; j2 < 4; ++j2) acc[i][j2] = f32x4{0.f, 0.f, 0.f, 0.f};

  const int nk = klen >> 6;
  // prologue: stage tile 0
#pragma unroll
  for (int s2 = 0; s2 < 4; ++s2) GLD16(Ag[s2], &lds[0][dstE[s2]]);
#pragma unroll
  for (int s2 = 0; s2 < 4; ++s2) GLD16(Bg[s2], &lds[0][16384 + dstE[s2]]);
  asm volatile("s_waitcnt vmcnt(0)" ::: "memory");   // my tile-0 loads landed
  __builtin_amdgcn_s_barrier();                      // => ALL waves' landed (R4 rule)

  int cur = 0;
  for (int t = 0; t < nk; ++t) {
    const bool more = (t + 1 < nk);
    // next-tile GLDs first (max in-flight time). Overwrites lds[cur^1] =
    // tile t-1: all waves' reads of it completed before their iter-(t-1)
    // MFMA, hence before the iter-(t-1) barrier (R6-proven).
    if (more) {
      const int kn = (t + 1) << 6;
#pragma unroll
      for (int s2 = 0; s2 < 4; ++s2) GLD16(Ag[s2] + kn, &lds[cur ^ 1][dstE[s2]]);
#pragma unroll
      for (int s2 = 0; s2 < 4; ++s2) GLD16(Bg[s2] + kn, &lds[cur ^ 1][16384 + dstE[s2]]);
    }
    s16x8 a0[8], b0[4], a1[8], b1[4];
#pragma unroll
    for (int mf = 0; mf < 8; ++mf) a0[mf] = *(const s16x8*)&lds[cur][abase + mf * 1024 + colx0];
#pragma unroll
    for (int nf = 0; nf < 4; ++nf) b0[nf] = *(const s16x8*)&lds[cur][bbase + nf * 1024 + colx0];
#pragma unroll
    for (int mf = 0; mf < 8; ++mf) a1[mf] = *(const s16x8*)&lds[cur][abase + mf * 1024 + colx1];
#pragma unroll
    for (int nf = 0; nf < 4; ++nf) b1[nf] = *(const s16x8*)&lds[cur][bbase + nf * 1024 + colx1];
    __builtin_amdgcn_s_setprio(1);
#pragma unroll
    for (int mf = 0; mf < 8; ++mf)
#pragma unroll
      for (int nf = 0; nf < 4; ++nf) acc[mf][nf] = mfma16(a0[mf], b0[nf], acc[mf][nf]);
#pragma unroll
    for (int mf = 0; mf < 8; ++mf)
#pragma unroll
      for (int nf = 0; nf < 4; ++nf) acc[mf][nf] = mfma16(a1[mf], b1[nf], acc[mf][nf]);
    __builtin_amdgcn_s_setprio(0);
    if (more) {
      asm volatile("s_waitcnt vmcnt(0)" ::: "memory");
      __builtin_amdgcn_s_barrier();
      cur ^= 1;
    }
  }

  // ---- epilogue: LDS-staged, full-cache-line vectorized stores (R8) ----
  float* fst = (float*)(void*)&lds[0][0];
#pragma unroll
  for (int mf = 0; mf < 8; ++mf) {
    __builtin_amdgcn_s_barrier();        // prior round's LDS reads complete
#pragma unroll
    for (int nf = 0; nf < 4; ++nf) {
      int cl = wn * 64 + nf * 16 + lr;
      float bv = 0.f;
      if (OMODE != 4) bv = bias[n0 + cl];
      int rl = wm * 16 + g * 4;
#pragma unroll
      for (int r = 0; r < 4; ++r) {
        float v = acc[mf][nf][r] + bv;
        if (RELU) v = fmaxf(v, 0.f);
        fst[(rl + r) * 260 + cl] = v;    // banks: 2-way (free)
      }
    }
    __builtin_amdgcn_s_barrier();
    if (OMODE == 0 || OMODE == 4) {
      // 32 rows x 256 x 16-bit = 1024 segs of 16B
      u16* Ch = (OMODE == 4)
              ? ((u16*)Cp + (size_t)split * ((size_t)M * N))
              : (u16*)Cp;
#pragma unroll
      for (int it = 0; it < 2; ++it) {
        int seg = it * 512 + tid;
        int row = seg >> 5;
        int co  = (seg & 31) * 8;
        int grow = m0 + (row >> 4) * 128 + mf * 16 + (row & 15);
        const float* src = &fst[row * 260 + co];
        uint4 q;
        if (OMODE == 0) {
          q.x = (u32)f2bf(src[0]) | ((u32)f2bf(src[1]) << 16);
          q.y = (u32)f2bf(src[2]) | ((u32)f2bf(src[3]) << 16);
          q.z = (u32)f2bf(src[4]) | ((u32)f2bf(src[5]) << 16);
          q.w = (u32)f2bf(src[6]) | ((u32)f2bf(src[7]) << 16);
        } else {
          q.x = (u32)f2h(src[0]) | ((u32)f2h(src[1]) << 16);
          q.y = (u32)f2h(src[2]) | ((u32)f2h(src[3]) << 16);
          q.z = (u32)f2h(src[4]) | ((u32)f2h(src[5]) << 16);
          q.w = (u32)f2h(src[6]) | ((u32)f2h(src[7]) << 16);
        }
        *(uint4*)&Ch[(size_t)grow * N + n0 + co] = q;
      }
    } else {
      // 32 rows x 256 f32 = 2048 segs of 16B
#pragma unroll
      for (int it = 0; it < 4; ++it) {
        int seg = it * 512 + tid;
        int row = seg >> 6;
        int co  = (seg & 63) * 4;
        int grow = m0 + (row >> 4) * 128 + mf * 16 + (row & 15);
        f32x4 q = *(const f32x4*)&fst[row * 260 + co];
        *(f32x4*)&((float*)Cp)[(size_t)grow * N + n0 + co] = q;
      }
    }
  }
}

// ---------------- GEMM 128x128, 4 waves, ring-2, 1 barrier/K-tile --------
// For N=1024 shapes (Wo, FF2 fallback). OMODE 1: f32 out + residual add.
template<int OMODE, int RELU>
__global__ __launch_bounds__(256, 3) void gemm_p(
    const u16* __restrict__ A, const u16* __restrict__ Bt,
    const float* __restrict__ bias, const float* res, void* Cp,
    int M, int N, int K, int gx)
{
  __shared__ alignas(16) u16 lds[2][8192];
  const int tid = threadIdx.x;
  const int w = tid >> 6, l = tid & 63;
  const int g = l >> 4, lr = l & 15;
  const int wm = w >> 1, wn = w & 1;
  int nwg = gridDim.x;
  int bid = blockIdx.x;
  int swz = (bid & 7) * (nwg >> 3) + (bid >> 3);
  int bx = swz % gx, by = swz / gx;
  int m0 = by << 7, n0 = bx << 7;

  const u16 *Ag[2], *Bg[2];
  int dstA[2], dstB[2];
#pragma unroll
  for (int s = 0; s < 2; ++s) {
    int idx = s * 256 + tid;
    int row = idx >> 2;
    int ch = (idx & 3) ^ ((row >> 1) & 3);
    Ag[s] = A  + (size_t)(m0 + row) * K + ch * 8;
    Bg[s] = Bt + (size_t)(n0 + row) * K + ch * 8;
    dstA[s] = idx * 8;
    dstB[s] = 4096 + idx * 8;
  }
  const int colx = (g ^ ((lr >> 1) & 3)) * 8;
  const int aoff = (wm * 64 + lr) * 32 + colx;
  const int boff = 4096 + (wn * 64 + lr) * 32 + colx;

  f32x4 acc[4][4];
#pragma unroll
  for (int i = 0; i < 4; ++i)
#pragma unroll
    for (int j = 0; j < 4; ++j) acc[i][j] = f32x4{0.f, 0.f, 0.f, 0.f};

  const int nk = K >> 5;
#pragma unroll
  for (int s = 0; s < 2; ++s) GLD16(Ag[s], &lds[0][dstA[s]]);
#pragma unroll
  for (int s = 0; s < 2; ++s) GLD16(Bg[s], &lds[0][dstB[s]]);
  asm volatile("s_waitcnt vmcnt(0)" ::: "memory");
  __builtin_amdgcn_s_barrier();

  int cur = 0;
  s16x8 aC[4], bC[4];
#pragma unroll
  for (int i = 0; i < 4; ++i) aC[i] = *(const s16x8*)&lds[0][aoff + i * 512];
#pragma unroll
  for (int j = 0; j < 4; ++j) bC[j] = *(const s16x8*)&lds[0][boff + j * 512];

  for (int t = 0; t < nk; ++t) {
    const bool more = (t + 1 < nk);
    if (more) {
      const int kn = (t + 1) << 5;
#pragma unroll
      for (int s = 0; s < 2; ++s) GLD16(Ag[s] + kn, &lds[cur ^ 1][dstA[s]]);
#pragma unroll
      for (int s = 0; s < 2; ++s) GLD16(Bg[s] + kn, &lds[cur ^ 1][dstB[s]]);
    }
    __builtin_amdgcn_s_setprio(1);
#pragma unroll
    for (int i = 0; i < 4; ++i)
#pragma unroll
      for (int j = 0; j < 4; ++j) acc[i][j] = mfma16(aC[i], bC[j], acc[i][j]);
    __builtin_amdgcn_s_setprio(0);
    if (more) {
      asm volatile("s_waitcnt vmcnt(0)" ::: "memory");
      __builtin_amdgcn_s_barrier();
      cur ^= 1;
#pragma unroll
      for (int i = 0; i < 4; ++i) aC[i] = *(const s16x8*)&lds[cur][aoff + i * 512];
#pragma unroll
      for (int j = 0; j < 4; ++j) bC[j] = *(const s16x8*)&lds[cur][boff + j * 512];
    }
  }
#pragma unroll
  for (int mf = 0; mf < 4; ++mf) {
    int row = m0 + wm * 64 + mf * 16 + g * 4;
#pragma unroll
    for (int nf = 0; nf < 4; ++nf) {
      int col = n0 + wn * 64 + nf * 16 + lr;
      float bv = bias[col];
#pragma unroll
      for (int r = 0; r < 4; ++r) {
        float v = acc[mf][nf][r] + bv;
        if (RELU) v = fmaxf(v, 0.f);
        size_t idx = (size_t)(row + r) * N + col;
        if (OMODE == 0)      ((u16*)Cp)[idx] = f2bf(v);
        else if (OMODE == 1) ((float*)Cp)[idx] = v + res[idx];
        else                 ((float*)Cp)[idx] = v;
      }
    }
  }
}

// ---------------- flash attention (no setprio: lockstep regime) ---------
__global__ __launch_bounds__(256) void attn_kernel(
    const u16* __restrict__ qkv, u16* __restrict__ outp)
{
  int b = blockIdx.x >> 4, h = blockIdx.x & 15;
  int q0 = blockIdx.y << 6;
  int tid = threadIdx.x, w = tid >> 6, l = tid & 63;
  int g = l >> 4, lr = l & 15;
  const int RS = 3072;
  const u16* base = qkv + (size_t)b * 1024 * RS + h * 64;
  const u16* Qb = base;
  const u16* Kb = base + 1024;
  const u16* Vb = base + 2048;
  __shared__ alignas(16) u16 Plds[4][1024];
  __shared__ alignas(16) u16 Vt[4096];
  char* Pw = (char*)&Plds[w][0];

  s16x8 qf[2];
#pragma unroll
  for (int ks = 0; ks < 2; ++ks)
    qf[ks] = *(const s16x8*)&Qb[(size_t)(q0 + w * 16 + lr) * RS + ks * 32 + g * 8];

  f32x4 o[4];
#pragma unroll
  for (int n = 0; n < 4; ++n) o[n] = f32x4{0.f, 0.f, 0.f, 0.f};
  float mr[4] = {-INFINITY, -INFINITY, -INFINITY, -INFINITY};
  float ls[4] = {0.f, 0.f, 0.f, 0.f};

  int ntile = (q0 >> 6) + 1;
  for (int kt = 0; kt < ntile; ++kt) {
    int kv0 = kt << 6;
    f32x4 sc[4];
#pragma unroll
    for (int t = 0; t < 4; ++t) sc[t] = f32x4{0.f, 0.f, 0.f, 0.f};
#pragma unroll
    for (int ks = 0; ks < 2; ++ks)
#pragma unroll
      for (int t = 0; t < 4; ++t) {
        s16x8 kf = *(const s16x8*)&Kb[(size_t)(kv0 + t * 16 + lr) * RS + ks * 32 + g * 8];
        sc[t] = mfma16(qf[ks], kf, sc[t]);
      }
#pragma unroll
    for (int p = 0; p < 2; ++p) {
      int key = p * 32 + (tid >> 3);
      int d0 = (tid & 7) * 8;
      s16x8 vrow = *(const s16x8*)&Vb[(size_t)(kv0 + key) * RS + d0];
#pragma unroll
      for (int j = 0; j < 8; ++j) {
        int d = d0 + j;
        int byt = (d * 128 + key * 2) ^ ((d & 7) << 4);
        *(u16*)((char*)Vt + byt) = (u16)vrow[j];
      }
    }
    float p4[4][4];
    float tmax[4] = {-INFINITY, -INFINITY, -INFINITY, -INFINITY};
    int qr_base = q0 + w * 16 + g * 4;
#pragma unroll
    for (int t = 0; t < 4; ++t) {
      int key = kv0 + t * 16 + lr;
#pragma unroll
      for (int r = 0; r < 4; ++r) {
        float s = sc[t][r] * 0.125f;
        s = (key <= qr_base + r) ? s : -1e30f;
        p4[t][r] = s;
        tmax[r] = fmaxf(tmax[r], s);
      }
    }
#pragma unroll
    for (int off = 1; off < 16; off <<= 1)
#pragma unroll
      for (int r = 0; r < 4; ++r) tmax[r] = fmaxf(tmax[r], __shfl_xor(tmax[r], off, 64));
    float corr[4], rsum[4];
#pragma unroll
    for (int r = 0; r < 4; ++r) {
      float mn = fmaxf(mr[r], tmax[r]);
      corr[r] = __expf(mr[r] - mn);
      mr[r] = mn;
      rsum[r] = 0.f;
    }
#pragma unroll
    for (int t = 0; t < 4; ++t)
#pragma unroll
      for (int r = 0; r < 4; ++r) {
        float e = __expf(p4[t][r] - mr[r]);
        p4[t][r] = e;
        rsum[r] += e;
      }
#pragma unroll
    for (int off = 1; off < 16; off <<= 1)
#pragma unroll
      for (int r = 0; r < 4; ++r) rsum[r] += __shfl_xor(rsum[r], off, 64);
#pragma unroll
    for (int r = 0; r < 4; ++r) ls[r] = ls[r] * corr[r] + rsum[r];
#pragma unroll
    for (int n = 0; n < 4; ++n)
#pragma unroll
      for (int r = 0; r < 4; ++r) o[n][r] *= corr[r];
#pragma unroll
    for (int t = 0; t < 4; ++t)
#pragma unroll
      for (int r = 0; r < 4; ++r) {
        int prow = g * 4 + r;
        int byt = (prow * 128 + (t * 16 + lr) * 2) ^ ((prow & 7) << 4);
        *(u16*)(Pw + byt) = f2bf(p4[t][r]);
      }
    __syncthreads();
#pragma unroll
    for (int ks = 0; ks < 2; ++ks) {
      int ab = (lr * 128 + ks * 64 + g * 16) ^ ((lr & 7) << 4);
      s16x8 pa = *(const s16x8*)(Pw + ab);
#pragma unroll
      for (int n = 0; n < 4; ++n) {
        int vb2 = ((n * 16 + lr) * 128 + ks * 64 + g * 16) ^ ((lr & 7) << 4);
        s16x8 vfr = *(const s16x8*)((const char*)Vt + vb2);
        o[n] = mfma16(pa, vfr, o[n]);
      }
    }
    __syncthreads();
  }
#pragma unroll
  for (int n = 0; n < 4; ++n)
#pragma unroll
    for (int r = 0; r < 4; ++r) {
      float v = o[n][r] / ls[r];
      outp[(size_t)(b * 1024 + q0 + w * 16 + g * 4 + r) * 1024 + h * 64 + n * 16 + lr] = f2bf(v);
    }
}

// ---------------- launch ----------------
extern "C" void kernel_launch(void* const* d_in, const int* in_sizes, int n_in,
                              void* d_out, int out_size, void* d_ws, size_t ws_size,
                              hipStream_t stream)
{
  const int*   tokens = (const int*)  d_in[0];
  const float* embW   = (const float*)d_in[1];
  const float* Wq     = (const float*)d_in[2];
  const float* bq     = (const float*)d_in[3];
  const float* Wk     = (const float*)d_in[4];
  const float* bk     = (const float*)d_in[5];
  const float* Wv     = (const float*)d_in[6];
  const float* bv     = (const float*)d_in[7];
  const float* Wo     = (const float*)d_in[8];
  const float* bo     = (const float*)d_in[9];
  const float* ln1g   = (const float*)d_in[10];
  const float* ln1b   = (const float*)d_in[11];
  const float* ln2g   = (const float*)d_in[12];
  const float* ln2b   = (const float*)d_in[13];
  const float* W1     = (const float*)d_in[14];
  const float* b1     = (const float*)d_in[15];
  const float* W2     = (const float*)d_in[16];
  const float* b2     = (const float*)d_in[17];
  const float* lnfg   = (const float*)d_in[18];
  const float* lnfb   = (const float*)d_in[19];
  const float* headW  = (const float*)d_in[20];
  const float* headb  = (const float*)d_in[21];
  (void)in_sizes; (void)n_in; (void)out_size;

  char* ws = (char*)d_ws;
  u16*   qkvT = (u16*)(ws);               // [8][3072][1024] bf16
  u16*   woT  = (u16*)(ws + 50331648);    // [8][1024][1024]
  u16*   w1T  = (u16*)(ws + 67108864);    // [8][4096][1024]
  u16*   w2T  = (u16*)(ws + 134217728);   // [8][1024][4096]
  u16*   headT= (u16*)(ws + 201326592);   // [32000][1024]
  float* bqkv = (float*)(ws + 266862592); // [8][3072]
  float* x    = (float*)(ws + 266960896); // [4096][1024] f32 residual stream
  u16*   y    = (u16*)(ws + 283738112);   // [4096][1024] bf16 LN output
  u16*   qkv  = (u16*)(ws + 292126720);   // [4096][3072] bf16
  u16*   attno= (u16*)(ws + 317292544);   // [4096][1024] bf16
  u16*   h1   = (u16*)(ws + 325681152);   // [4096][4096] bf16
  u16*   pbuf = (u16*)(ws + 359235584);   // [4][4096][1024] f16 (32MB, optional)
  if (ws_size < 359235584ull) return;     // base scratch requirement
  const bool splitk = (ws_size >= 392790016ull);  // + 32MB f16 partials

  dim3 blk(256);
  dim3 blk5(512);
  // weight prep (transpose_cvt2: in rows = bx*64, in cols = by*32)
  transpose_cvt2<<<dim3(16, 32, 8),  blk, 0, stream>>>(Wq, qkvT,           1024,  1048576LL, 3145728LL, 1024);
  transpose_cvt2<<<dim3(16, 32, 8),  blk, 0, stream>>>(Wk, qkvT + 1048576, 1024,  1048576LL, 3145728LL, 1024);
  transpose_cvt2<<<dim3(16, 32, 8),  blk, 0, stream>>>(Wv, qkvT + 2097152, 1024,  1048576LL, 3145728LL, 1024);
  transpose_cvt2<<<dim3(16, 32, 8),  blk, 0, stream>>>(Wo, woT,            1024,  1048576LL, 1048576LL, 1024);
  transpose_cvt2<<<dim3(16, 128, 8), blk, 0, stream>>>(W1, w1T,            4096,  4194304LL, 4194304LL, 1024);
  transpose_cvt2<<<dim3(64, 32, 8),  blk, 0, stream>>>(W2, w2T,            1024,  4194304LL, 4194304LL, 4096);
  transpose_cvt2<<<dim3(16, 1000, 1),blk, 0, stream>>>(headW, headT,       32000, 0LL,       0LL,       1024);
  pack_bqkv<<<96, blk, 0, stream>>>(bq, bk, bv, bqkv);
  // embedding + first LN
  embed_kernel<<<4096, blk, 0, stream>>>(tokens, embW, x);
  ln_kernel<<<4096, blk, 0, stream>>>(x, ln1g, ln1b, y);
  // layers
  for (int ly = 0; ly < 8; ++ly) {
    // QKV: gy=16, gxp8=2, real gx=12 -> grid 256
    gemm256<0, 0, 0><<<256, blk5, 0, stream>>>(y, 1024,
        qkvT + (size_t)ly * 3145728, bqkv + ly * 3072, qkv,
        4096, 3072, 1024, 2, 12);
    attn_kernel<<<dim3(64, 16), blk, 0, stream>>>(qkv, attno);
    // Wo: gemm_p with fused residual (R14-proven; split-K loses here)
    gemm_p<1, 0><<<256, blk, 0, stream>>>(attno, woT + (size_t)ly * 1048576,
        bo + ly * 1024, x, x, 4096, 1024, 1024, 8);
    ln_kernel<<<4096, blk, 0, stream>>>(x, ln2g + ly * 1024, ln2b + ly * 1024, y);
    // FF1: gy=16, gxp8=2, real gx=16 -> grid 256
    gemm256<0, 1, 0><<<256, blk5, 0, stream>>>(y, 1024,
        w1T + (size_t)ly * 4194304, b1 + ly * 4096, h1,
        4096, 4096, 1024, 2, 16);
    const float* ng = (ly < 7) ? (ln1g + (ly + 1) * 1024) : lnfg;
    const float* nb = (ly < 7) ? (ln1b + (ly + 1) * 1024) : lnfb;
    if (splitk) {
      // FF2 split-K=4 (f16 partials); then reduce + residual + next-LN
      gemm256<4, 0, 1><<<256, blk5, 0, stream>>>(h1, 4096,
          w2T + (size_t)ly * 4194304, nullptr, pbuf,
          4096, 1024, 1024, 0, 0);
      red_ln<<<4096, blk, 0, stream>>>(pbuf, b2 + ly * 1024, x, ng, nb, y);
    } else {
      gemm_p<1, 0><<<256, blk, 0, stream>>>(h1, w2T + (size_t)ly * 4194304,
          b2 + ly * 1024, x, x, 4096, 1024, 4096, 8);
      ln_kernel<<<4096, blk, 0, stream>>>(x, ng, nb, y);
    }
  }
  // head: gy=16, gxp8=16, real gx=125 -> grid 2048
  gemm256<2, 0, 0><<<2048, blk5, 0, stream>>>(y, 1024, headT, headb,
      (float*)d_out, 4096, 32000, 1024, 16, 125);
}